// Round 3
// baseline (41767.535 us; speedup 1.0000x reference)
//
#include <hip/hip_runtime.h>
#include <math.h>

#define BB 128
#define TT 256
#define DD 512
#define HH 1024
#define G4H 4096
#define CO 7

typedef __attribute__((ext_vector_type(8))) short bf16x8;
typedef __attribute__((ext_vector_type(4))) float f32x4;

__device__ __forceinline__ unsigned short f2bf(float f) {
  unsigned int u = __float_as_uint(f);
  unsigned int r = (u + 0x7fffu + ((u >> 16) & 1u)) >> 16;
  return (unsigned short)r;
}
__device__ __forceinline__ float bf2f(unsigned short h) {
  return __uint_as_float(((unsigned int)h) << 16);
}
__device__ __forceinline__ float tanh_fast(float x) {
  x = fminf(fmaxf(x, -15.f), 15.f);
  const float e = __expf(2.f * x);
  return (e - 1.f) / (e + 1.f);
}
__device__ __forceinline__ float sigmoid_fast(float x) {
  return 1.f / (1.f + __expf(-x));
}

// ------------------------------------------------------------------
// Pack weight W[N][K] fp32 -> fragment-major bf16 hi/lo:
// pk[(((nt*KS + ks)*2 + hilo)*64 + lane)*8 + e] = W[srow(nt*16+(l&15))][ks*32+(l>>4)*8+e]
// perm: srow(n) = (n&3)*1024 + (n>>6)*16 + ((n>>2)&15)  (gate-interleaved WG order)
// ------------------------------------------------------------------
__global__ __launch_bounds__(256)
void pack_w(const float* __restrict__ W, unsigned short* __restrict__ pk,
            int N, int K, int perm) {
  const int KS = K >> 5;
  const int idx = blockIdx.x * 256 + threadIdx.x;
  const int total = (N >> 4) * KS * 64;
  if (idx >= total) return;
  const int l = idx & 63;
  const int t2 = idx >> 6;
  const int ks = t2 & (KS - 1);
  const int nt = t2 / KS;
  const int n = (nt << 4) + (l & 15);
  const int srow = perm ? (((n & 3) << 10) + ((n >> 6) << 4) + ((n >> 2) & 15)) : n;
  const int scol = (ks << 5) + ((l >> 4) << 3);
  const float* src = W + (size_t)srow * K + scol;
  unsigned short hi[8], lo[8];
#pragma unroll
  for (int e = 0; e < 8; ++e) {
    const float v = src[e];
    const unsigned short h = f2bf(v);
    hi[e] = h;
    lo[e] = f2bf(v - bf2f(h));
  }
  const size_t base = (((size_t)nt * KS + ks) * 2) * 512 + (size_t)l * 8;
  *(uint4*)(pk + base) = *(const uint4*)hi;
  *(uint4*)(pk + base + 512) = *(const uint4*)lo;
}

// ------------------------------------------------------------------
// fp32 rows -> bf16 hi/lo arrays. Row r maps to src + (r>>lt)*sOut + (r&msk)*sIn.
// ------------------------------------------------------------------
__global__ __launch_bounds__(256)
void cvt_rows(const float* __restrict__ src, long long sOut, long long sIn, int lt,
              unsigned short* __restrict__ hi, unsigned short* __restrict__ lo,
              int K, int rows) {
  const int idx = blockIdx.x * 256 + threadIdx.x;
  const int perRow = K >> 2;
  const int r = idx / perRow;
  if (r >= rows) return;
  const int c4 = (idx - r * perRow) << 2;
  const float* s = src + (size_t)(r >> lt) * sOut + (size_t)(r & ((1 << lt) - 1)) * sIn + c4;
  const float4 v = *(const float4*)s;
  unsigned short h4[4], l4v[4];
  const float vv[4] = {v.x, v.y, v.z, v.w};
#pragma unroll
  for (int e = 0; e < 4; ++e) {
    const unsigned short h = f2bf(vv[e]);
    h4[e] = h;
    l4v[e] = f2bf(vv[e] - bf2f(h));
  }
  const size_t o = (size_t)r * K + c4;
  *(uint2*)(hi + o) = *(const uint2*)h4;
  *(uint2*)(lo + o) = *(const uint2*)l4v;
}

// ------------------------------------------------------------------
// Big GEMM (bf16x3 MFMA, no LDS): C[r][n_pk] = Ahi/lo(r,:) . Wpk(n_pk,:) + bias
// Grid (N/64, M/128), 512 threads (8 waves = 2 Mhalves x 4 Ntiles).
// A: row-major bf16 hi/lo [M][K]. pk: fragment-packed (pack_w). C fp32 [M][4096].
// ------------------------------------------------------------------
__global__ __launch_bounds__(512)
void gemm_mfma(const unsigned short* __restrict__ Ahi, const unsigned short* __restrict__ Alo,
               const unsigned short* __restrict__ pk,
               const float* __restrict__ b0, const float* __restrict__ b1,
               float* __restrict__ C, int M, int K, int perm) {
  const int KS = K >> 5;
  const int tid = threadIdx.x;
  const int wid = tid >> 6, l = tid & 63;
  const int mh = wid & 1, ng = wid >> 1;
  const int bm = blockIdx.y << 7;
  const int wn = blockIdx.x;
  const int l15 = l & 15, l4 = l >> 4;

  f32x4 acc[4];
#pragma unroll
  for (int mt = 0; mt < 4; ++mt) acc[mt] = (f32x4)(0.f);

  const int rowb = bm + (mh << 6) + l15;
  const unsigned short* ah[4];
  const unsigned short* al[4];
#pragma unroll
  for (int mt = 0; mt < 4; ++mt) {
    ah[mt] = Ahi + (size_t)(rowb + (mt << 4)) * K;
    al[mt] = Alo + (size_t)(rowb + (mt << 4)) * K;
  }
  const int nt = (wn << 2) + ng;
  const unsigned short* pkb = pk + (size_t)nt * KS * 1024 + (size_t)l * 8;

  for (int ks = 0; ks < KS; ++ks) {
    const bf16x8 bh = *(const bf16x8*)(pkb + (size_t)ks * 1024);
    const bf16x8 bl = *(const bf16x8*)(pkb + (size_t)ks * 1024 + 512);
    const int kof = (ks << 5) + (l4 << 3);
#pragma unroll
    for (int mt = 0; mt < 4; ++mt) {
      const bf16x8 a_h = *(const bf16x8*)(ah[mt] + kof);
      const bf16x8 a_l = *(const bf16x8*)(al[mt] + kof);
      acc[mt] = __builtin_amdgcn_mfma_f32_16x16x32_bf16(a_h, bh, acc[mt], 0, 0, 0);
      acc[mt] = __builtin_amdgcn_mfma_f32_16x16x32_bf16(a_h, bl, acc[mt], 0, 0, 0);
      acc[mt] = __builtin_amdgcn_mfma_f32_16x16x32_bf16(a_l, bh, acc[mt], 0, 0, 0);
    }
  }

  const int n = (wn << 6) + (ng << 4) + l15;
  const int sn = perm ? (((n & 3) << 10) + ((n >> 6) << 4) + ((n >> 2) & 15)) : n;
  const float bias = b0[sn] + b1[sn];
#pragma unroll
  for (int mt = 0; mt < 4; ++mt) {
    const int rbase = bm + (mh << 6) + (mt << 4) + (l4 << 2);
#pragma unroll
    for (int r = 0; r < 4; ++r)
      C[(size_t)(rbase + r) * G4H + n] = acc[mt][r] + bias;
  }
}

// ------------------------------------------------------------------
// Fused LSTM step (bf16x3 MFMA): gates = gx + h_prev @ whh^T, cell, h out (hi/lo).
// Grid 64 WGs x 512 thr. WG w owns j in [w*16, w*16+16), all 4 gates, all 128 b.
// gx is in packed-n layout: gxt[b*gxbs + w*64 + nl], nl = jl*4 + g.
// ------------------------------------------------------------------
__global__ __launch_bounds__(512)
void lstm_step_mfma(const float* __restrict__ gxt, long long gxbs,
                    const unsigned short* __restrict__ pk,
                    const unsigned short* __restrict__ hphi,
                    const unsigned short* __restrict__ hplo, long long hpbs,
                    unsigned short* __restrict__ hohi,
                    unsigned short* __restrict__ holo, long long hobs,
                    float* __restrict__ cbuf, int kOn) {
  const int tid = threadIdx.x;
  const int wid = tid >> 6, l = tid & 63;
  const int mh = wid & 1, ng = wid >> 1;
  const int w = blockIdx.x;
  const int l15 = l & 15, l4 = l >> 4;
  const int nl = (ng << 4) + l15;

  f32x4 acc[4];
#pragma unroll
  for (int mt = 0; mt < 4; ++mt) {
    const int b0r = (mh << 6) + (mt << 4) + (l4 << 2);
#pragma unroll
    for (int r = 0; r < 4; ++r)
      acc[mt][r] = gxt[(size_t)(b0r + r) * gxbs + (w << 6) + nl];
  }

  if (kOn) {
    const int nt = (w << 2) + ng;
    const unsigned short* pkb = pk + (size_t)nt * 32 * 1024 + (size_t)l * 8;
    const unsigned short* hh0 = hphi + (size_t)((mh << 6) + l15) * hpbs;
    const unsigned short* hl0 = hplo + (size_t)((mh << 6) + l15) * hpbs;
    for (int ks = 0; ks < 32; ++ks) {
      const bf16x8 bh = *(const bf16x8*)(pkb + (size_t)ks * 1024);
      const bf16x8 bl = *(const bf16x8*)(pkb + (size_t)ks * 1024 + 512);
      const int kof = (ks << 5) + (l4 << 3);
#pragma unroll
      for (int mt = 0; mt < 4; ++mt) {
        const bf16x8 a_h = *(const bf16x8*)(hh0 + (size_t)(mt << 4) * hpbs + kof);
        const bf16x8 a_l = *(const bf16x8*)(hl0 + (size_t)(mt << 4) * hpbs + kof);
        acc[mt] = __builtin_amdgcn_mfma_f32_16x16x32_bf16(a_h, bh, acc[mt], 0, 0, 0);
        acc[mt] = __builtin_amdgcn_mfma_f32_16x16x32_bf16(a_h, bl, acc[mt], 0, 0, 0);
        acc[mt] = __builtin_amdgcn_mfma_f32_16x16x32_bf16(a_l, bh, acc[mt], 0, 0, 0);
      }
    }
  }

  const int g = l & 3;
  const int j = (w << 4) + (nl >> 2);
#pragma unroll
  for (int mt = 0; mt < 4; ++mt) {
    const int bb = (mh << 6) + (mt << 4) + (l4 << 2);
#pragma unroll
    for (int r = 0; r < 4; ++r) {
      const float v = acc[mt][r];
      const float v1 = __shfl_xor(v, 1);
      const float v2 = __shfl_xor(v, 2);
      const float v3 = __shfl_xor(v, 3);
      if (g == 0) {
        const int b = bb + r;
        const float si = sigmoid_fast(v);
        const float sf = sigmoid_fast(v1);
        const float tg = tanh_fast(v2);
        const float so = sigmoid_fast(v3);
        const size_t ci = (size_t)b * HH + j;
        const float cn = sf * cbuf[ci] + si * tg;
        cbuf[ci] = cn;
        const float h = so * tanh_fast(cn);
        const unsigned short hh = f2bf(h);
        const size_t ho = (size_t)b * hobs + j;
        hohi[ho] = hh;
        holo[ho] = f2bf(h - bf2f(hh));
      }
    }
  }
}

// ------------------------------------------------------------------
// FC from hi/lo h: out[b][n] = (hi+lo)[b] . fc_w[n] + fc_b[n]. One wave/output.
// ------------------------------------------------------------------
__global__ __launch_bounds__(256)
void fc_hilo(const unsigned short* __restrict__ hhi, const unsigned short* __restrict__ hlo,
             const float* __restrict__ fcw, const float* __restrict__ fcb,
             float* __restrict__ out) {
  const int gw = (int)((blockIdx.x * 256 + threadIdx.x) >> 6);
  const int lane = threadIdx.x & 63;
  const int b = gw / CO;
  const int n = gw - b * CO;
  const unsigned short* hp = hhi + (size_t)b * HH;
  const unsigned short* lp = hlo + (size_t)b * HH;
  const float* wp = fcw + (size_t)n * HH;
  float s = 0.f;
  for (int k = lane; k < HH; k += 64) s += (bf2f(hp[k]) + bf2f(lp[k])) * wp[k];
#pragma unroll
  for (int off = 32; off; off >>= 1) s += __shfl_down(s, off);
  if (lane == 0) out[b * CO + n] = s + fcb[n];
}

// ==================================================================
// Fallback fp32 path (round-2 kernels, used only if ws_size is small)
// ==================================================================
__global__ __launch_bounds__(256)
void gemm_bias(const float* __restrict__ A, long long sOut, long long sIn, int lt,
               const float* __restrict__ W,
               const float* __restrict__ b0, const float* __restrict__ b1,
               float* __restrict__ C, int N, int K) {
  __shared__ float as[16][64];
  __shared__ float wsh[16][64];
  const int tid = threadIdx.x;
  const int bm = blockIdx.y << 6;
  const int bn = blockIdx.x << 6;
  const int tr = (tid >> 4) << 2;
  const int tc = (tid & 15) << 2;
  const int lrow = tid >> 2;
  const int lk4 = (tid & 3) << 2;
  const int msk = (1 << lt) - 1;
  const int r = bm + lrow;
  const float* ap = A + (size_t)(r >> lt) * sOut + (size_t)(r & msk) * sIn + lk4;
  const float* wp = W + (size_t)(bn + lrow) * K + lk4;
  float acc[4][4] = {};
  for (int k0 = 0; k0 < K; k0 += 16) {
    const float4 av = *(const float4*)(ap + k0);
    const float4 wv = *(const float4*)(wp + k0);
    __syncthreads();
    as[lk4 + 0][lrow] = av.x; as[lk4 + 1][lrow] = av.y;
    as[lk4 + 2][lrow] = av.z; as[lk4 + 3][lrow] = av.w;
    wsh[lk4 + 0][lrow] = wv.x; wsh[lk4 + 1][lrow] = wv.y;
    wsh[lk4 + 2][lrow] = wv.z; wsh[lk4 + 3][lrow] = wv.w;
    __syncthreads();
#pragma unroll
    for (int k = 0; k < 16; ++k) {
      const float4 a = *(const float4*)&as[k][tr];
      const float4 b = *(const float4*)&wsh[k][tc];
      acc[0][0] += a.x * b.x; acc[0][1] += a.x * b.y; acc[0][2] += a.x * b.z; acc[0][3] += a.x * b.w;
      acc[1][0] += a.y * b.x; acc[1][1] += a.y * b.y; acc[1][2] += a.y * b.z; acc[1][3] += a.y * b.w;
      acc[2][0] += a.z * b.x; acc[2][1] += a.z * b.y; acc[2][2] += a.z * b.z; acc[2][3] += a.z * b.w;
      acc[3][0] += a.w * b.x; acc[3][1] += a.w * b.y; acc[3][2] += a.w * b.z; acc[3][3] += a.w * b.w;
    }
  }
  const float* bp0 = b0 + bn + tc;
  const float* bp1 = b1 + bn + tc;
#pragma unroll
  for (int i = 0; i < 4; ++i) {
    float* cp = C + (size_t)(bm + tr + i) * N + bn + tc;
#pragma unroll
    for (int j = 0; j < 4; ++j) cp[j] = acc[i][j] + bp0[j] + bp1[j];
  }
}

__global__ __launch_bounds__(256)
void lstm_step(const float* __restrict__ gx, long long gxstride,
               const float* __restrict__ whh,
               const float* __restrict__ hprev, long long pstride,
               float* __restrict__ hnext, long long nstride,
               float* __restrict__ cbuf) {
  __shared__ float hs[32][16];
  __shared__ float wsm[32][4][32];
  const int tid = threadIdx.x;
  const int jt = blockIdx.x << 5;
  const int bm = blockIdx.y << 4;
  const int col = tid & 31;
  const int rp = (tid >> 5) << 1;
  const int hr = tid >> 4;
  const int hk = (tid & 15) << 1;
  const int wrow = tid & 127;
  const int wg = wrow >> 5;
  const int wc = wrow & 31;
  const int wk = (tid >> 7) << 4;
  const float* wbase = whh + (size_t)(wg * HH + jt + wc) * HH + wk;
  const float* hbase = hprev + (size_t)(bm + hr) * pstride + hk;

  float acc[4][2] = {};
  for (int k0 = 0; k0 < HH; k0 += 32) {
    const float2 hv = *(const float2*)(hbase + k0);
    const float4 wv0 = *(const float4*)(wbase + k0);
    const float4 wv1 = *(const float4*)(wbase + k0 + 4);
    const float4 wv2 = *(const float4*)(wbase + k0 + 8);
    const float4 wv3 = *(const float4*)(wbase + k0 + 12);
    __syncthreads();
    hs[hk][hr] = hv.x; hs[hk + 1][hr] = hv.y;
    {
      const float wvv[16] = {wv0.x, wv0.y, wv0.z, wv0.w, wv1.x, wv1.y, wv1.z, wv1.w,
                             wv2.x, wv2.y, wv2.z, wv2.w, wv3.x, wv3.y, wv3.z, wv3.w};
#pragma unroll
      for (int i = 0; i < 16; ++i) wsm[wk + i][wg][wc] = wvv[i];
    }
    __syncthreads();
#pragma unroll
    for (int k = 0; k < 32; ++k) {
      const float2 a = *(const float2*)&hs[k][rp];
      const float wi = wsm[k][0][col];
      const float wf = wsm[k][1][col];
      const float wg_ = wsm[k][2][col];
      const float wo = wsm[k][3][col];
      acc[0][0] += a.x * wi;  acc[0][1] += a.y * wi;
      acc[1][0] += a.x * wf;  acc[1][1] += a.y * wf;
      acc[2][0] += a.x * wg_; acc[2][1] += a.y * wg_;
      acc[3][0] += a.x * wo;  acc[3][1] += a.y * wo;
    }
  }
#pragma unroll
  for (int rr = 0; rr < 2; ++rr) {
    const int b = bm + rp + rr;
    const int j = jt + col;
    const size_t gxo = (size_t)b * gxstride + j;
    const float gi = acc[0][rr] + gx[gxo];
    const float gf = acc[1][rr] + gx[gxo + HH];
    const float gg = acc[2][rr] + gx[gxo + 2 * HH];
    const float go = acc[3][rr] + gx[gxo + 3 * HH];
    const float si = 1.f / (1.f + expf(-gi));
    const float sf = 1.f / (1.f + expf(-gf));
    const float so = 1.f / (1.f + expf(-go));
    const size_t cidx = (size_t)b * HH + j;
    const float cn = sf * cbuf[cidx] + si * tanhf(gg);
    cbuf[cidx] = cn;
    hnext[(size_t)b * nstride + j] = so * tanhf(cn);
  }
}

__global__ __launch_bounds__(256)
void fc_kernel(const float* __restrict__ hlast, const float* __restrict__ fcw,
               const float* __restrict__ fcb, float* __restrict__ out) {
  const int gw = (int)((blockIdx.x * 256 + threadIdx.x) >> 6);
  const int lane = threadIdx.x & 63;
  const int b = gw / CO;
  const int n = gw - b * CO;
  const float* hp = hlast + (size_t)b * HH;
  const float* wp = fcw + (size_t)n * HH;
  float s = 0.f;
  for (int k = lane; k < HH; k += 64) s += hp[k] * wp[k];
#pragma unroll
  for (int off = 32; off; off >>= 1) s += __shfl_down(s, off);
  if (lane == 0) out[b * CO + n] = s + fcb[n];
}

// ==================================================================
extern "C" void kernel_launch(void* const* d_in, const int* in_sizes, int n_in,
                              void* d_out, int out_size, void* d_ws, size_t ws_size,
                              hipStream_t stream) {
  const float* x    = (const float*)d_in[0];
  const float* wih0 = (const float*)d_in[1];
  const float* whh0 = (const float*)d_in[2];
  const float* bih0 = (const float*)d_in[3];
  const float* bhh0 = (const float*)d_in[4];
  const float* wih1 = (const float*)d_in[5];
  const float* whh1 = (const float*)d_in[6];
  const float* bih1 = (const float*)d_in[7];
  const float* bhh1 = (const float*)d_in[8];
  const float* fcw  = (const float*)d_in[9];
  const float* fcb  = (const float*)d_in[10];
  float* out = (float*)d_out;

  // ---- workspace budget for the MFMA path ----
  const size_t pkWhhE = (size_t)G4H * HH * 2;   // ushorts (hi+lo)
  const size_t pkWih0E = (size_t)G4H * DD * 2;
  const size_t fixedB = (2 * pkWhhE + pkWih0E + pkWhhE) * 2   // packs (bytes)
                      + 2 * (size_t)BB * HH * 4               // c0, c1
                      + 4 * (size_t)BB * HH * 2;              // h1a/h1b hi+lo
  const size_t perTcB = (size_t)BB * DD * 2 * 2       // xc hi/lo
                      + (size_t)BB * HH * 2 * 2       // h0c hi/lo
                      + (size_t)BB * G4H * 4;         // gxc fp32

  int Tc = 64, lt = 6;
  while (Tc > 1 && fixedB + perTcB * Tc > ws_size) { Tc >>= 1; --lt; }

  if (fixedB + perTcB * Tc <= ws_size) {
    // ---------------- MFMA bf16x3 path ----------------
    char* p = (char*)d_ws;
    unsigned short* pk_whh0 = (unsigned short*)p; p += pkWhhE * 2;
    unsigned short* pk_whh1 = (unsigned short*)p; p += pkWhhE * 2;
    unsigned short* pk_wih0 = (unsigned short*)p; p += pkWih0E * 2;
    unsigned short* pk_wih1 = (unsigned short*)p; p += pkWhhE * 2;
    float* c0 = (float*)p; p += (size_t)BB * HH * 4;
    float* c1 = (float*)p; p += (size_t)BB * HH * 4;
    unsigned short* h1a_hi = (unsigned short*)p; p += (size_t)BB * HH * 2;
    unsigned short* h1a_lo = (unsigned short*)p; p += (size_t)BB * HH * 2;
    unsigned short* h1b_hi = (unsigned short*)p; p += (size_t)BB * HH * 2;
    unsigned short* h1b_lo = (unsigned short*)p; p += (size_t)BB * HH * 2;
    unsigned short* xc_hi = (unsigned short*)p; p += (size_t)BB * Tc * DD * 2;
    unsigned short* xc_lo = (unsigned short*)p; p += (size_t)BB * Tc * DD * 2;
    unsigned short* h0c_hi = (unsigned short*)p; p += (size_t)BB * Tc * HH * 2;
    unsigned short* h0c_lo = (unsigned short*)p; p += (size_t)BB * Tc * HH * 2;
    float* gxc = (float*)p;

    hipMemsetAsync(c0, 0, (size_t)BB * HH * 4, stream);
    hipMemsetAsync(c1, 0, (size_t)BB * HH * 4, stream);

    // pack weights (fragment-major, gate-interleaved permutation)
    {
      const int tWhh = (G4H >> 4) * (HH >> 5) * 64;
      const int tWih0 = (G4H >> 4) * (DD >> 5) * 64;
      pack_w<<<dim3((tWhh + 255) / 256), 256, 0, stream>>>(whh0, pk_whh0, G4H, HH, 1);
      pack_w<<<dim3((tWhh + 255) / 256), 256, 0, stream>>>(whh1, pk_whh1, G4H, HH, 1);
      pack_w<<<dim3((tWih0 + 255) / 256), 256, 0, stream>>>(wih0, pk_wih0, G4H, DD, 1);
      pack_w<<<dim3((tWhh + 255) / 256), 256, 0, stream>>>(wih1, pk_wih1, G4H, HH, 1);
    }

    const int M = BB * Tc;
    const dim3 gGemm(G4H / 64, M / 128);
    const long long gxbs = (long long)Tc * G4H;
    const long long h0bs = (long long)Tc * HH;
    const int nChunks = TT / Tc;

    for (int ci = 0; ci < nChunks; ++ci) {
      const int t0 = ci * Tc;

      // x chunk -> bf16 hi/lo  (row r=b*Tc+tl -> x[b][t0+tl][:])
      {
        const int tot = M * (DD >> 2);
        cvt_rows<<<dim3((tot + 255) / 256), 256, 0, stream>>>(
            x + (size_t)t0 * DD, (long long)TT * DD, (long long)DD, lt,
            xc_hi, xc_lo, DD, M);
      }
      // layer-0 input GEMM
      gemm_mfma<<<gGemm, 512, 0, stream>>>(xc_hi, xc_lo, pk_wih0, bih0, bhh0,
                                           gxc, M, DD, 1);
      // layer-0 recurrence
      for (int tl = 0; tl < Tc; ++tl) {
        const int t = t0 + tl;
        const int ptl = (tl == 0) ? (Tc - 1) : (tl - 1);
        lstm_step_mfma<<<dim3(64), 512, 0, stream>>>(
            gxc + (size_t)tl * G4H, gxbs, pk_whh0,
            h0c_hi + (size_t)ptl * HH, h0c_lo + (size_t)ptl * HH, h0bs,
            h0c_hi + (size_t)tl * HH, h0c_lo + (size_t)tl * HH, h0bs,
            c0, t > 0 ? 1 : 0);
      }
      // layer-1 input GEMM (consumes h0c, overwrites gxc)
      gemm_mfma<<<gGemm, 512, 0, stream>>>(h0c_hi, h0c_lo, pk_wih1, bih1, bhh1,
                                           gxc, M, HH, 1);
      // layer-1 recurrence (ping-pong)
      for (int tl = 0; tl < Tc; ++tl) {
        const int t = t0 + tl;
        const unsigned short* hp_hi = ((t - 1) & 1) ? h1b_hi : h1a_hi;
        const unsigned short* hp_lo = ((t - 1) & 1) ? h1b_lo : h1a_lo;
        unsigned short* hn_hi = (t & 1) ? h1b_hi : h1a_hi;
        unsigned short* hn_lo = (t & 1) ? h1b_lo : h1a_lo;
        lstm_step_mfma<<<dim3(64), 512, 0, stream>>>(
            gxc + (size_t)tl * G4H, gxbs, pk_whh1,
            hp_hi, hp_lo, (long long)HH,
            hn_hi, hn_lo, (long long)HH,
            c1, t > 0 ? 1 : 0);
      }
    }

    fc_hilo<<<dim3((BB * CO * 64) / 256), 256, 0, stream>>>(h1b_hi, h1b_lo, fcw, fcb, out);
    return;
  }

  // ---------------- fallback fp32 path (round-2) ----------------
  {
    int Tc2 = 64, lt2 = 6;
    while (Tc2 > 1) {
      size_t need = ((size_t)655360 * (size_t)Tc2 + 4u * 131072u + 1024u) * 4u;
      if (need <= ws_size) break;
      Tc2 >>= 1; --lt2;
    }
    float* ws  = (float*)d_ws;
    float* gxc = ws;
    float* hc  = gxc + (size_t)BB * Tc2 * G4H;
    float* c0  = hc + (size_t)BB * Tc2 * HH;
    float* c1  = c0 + (size_t)BB * HH;
    float* h2a = c1 + (size_t)BB * HH;
    float* h2b = h2a + (size_t)BB * HH;
    float* zb  = h2b + (size_t)BB * HH;

    hipMemsetAsync(zb, 0, HH * sizeof(float), stream);
    hipMemsetAsync(c0, 0, (size_t)BB * HH * sizeof(float), stream);
    hipMemsetAsync(c1, 0, (size_t)BB * HH * sizeof(float), stream);

    const dim3 gGemm(G4H / 64, (BB * Tc2) / 64);
    const dim3 gStep(HH / 32, BB / 16);
    const long long gxs = (long long)Tc2 * G4H;
    const long long hcs = (long long)Tc2 * HH;

    const int nChunks = TT / Tc2;
    for (int ci = 0; ci < nChunks; ++ci) {
      const int t0 = ci * Tc2;
      gemm_bias<<<gGemm, 256, 0, stream>>>(x + (size_t)t0 * DD, (long long)TT * DD,
                                           (long long)DD, lt2, wih0, bih0, bhh0,
                                           gxc, G4H, DD);
      for (int tl = 0; tl < Tc2; ++tl) {
        const int t = t0 + tl;
        const float* hprev;
        long long ps;
        if (t == 0) { hprev = zb; ps = 0; }
        else {
          const int ptl = (tl == 0) ? (Tc2 - 1) : (tl - 1);
          hprev = hc + (size_t)ptl * HH; ps = hcs;
        }
        lstm_step<<<gStep, 256, 0, stream>>>(gxc + (size_t)tl * G4H, gxs, whh0,
                                             hprev, ps, hc + (size_t)tl * HH, hcs, c0);
      }
      gemm_bias<<<gGemm, 256, 0, stream>>>(hc, hcs, (long long)HH, lt2,
                                           wih1, bih1, bhh1, gxc, G4H, HH);
      for (int tl = 0; tl < Tc2; ++tl) {
        const int t = t0 + tl;
        const float* hprev;
        long long ps;
        if (t == 0) { hprev = zb; ps = 0; }
        else { hprev = ((t - 1) & 1) ? h2b : h2a; ps = HH; }
        float* hnext = (t & 1) ? h2b : h2a;
        lstm_step<<<gStep, 256, 0, stream>>>(gxc + (size_t)tl * G4H, gxs, whh1,
                                             hprev, ps, hnext, HH, c1);
      }
    }
    fc_kernel<<<dim3((BB * CO * 64) / 256), 256, 0, stream>>>(h2b, fcw, fcb, out);
  }
}

// Round 4
// 33743.649 us; speedup vs baseline: 1.2378x; 1.2378x over previous
//
#include <hip/hip_runtime.h>
#include <math.h>

#define BB 128
#define TT 256
#define DD 512
#define HH 1024
#define G4H 4096
#define CO 7
#define XROW (TT * DD)   // x row stride per batch (fp32 elements)

typedef __attribute__((ext_vector_type(8))) short bf16x8;
typedef __attribute__((ext_vector_type(4))) float f32x4;

__device__ __forceinline__ unsigned short f2bf(float f) {
  unsigned int u = __float_as_uint(f);
  unsigned int r = (u + 0x7fffu + ((u >> 16) & 1u)) >> 16;
  return (unsigned short)r;
}
__device__ __forceinline__ float bf2f(unsigned short h) {
  return __uint_as_float(((unsigned int)h) << 16);
}
__device__ __forceinline__ float tanh_fast(float x) {
  x = fminf(fmaxf(x, -15.f), 15.f);
  const float e = __expf(2.f * x);
  return (e - 1.f) / (e + 1.f);
}
__device__ __forceinline__ float sigmoid_fast(float x) {
  return 1.f / (1.f + __expf(-x));
}
// split 8 fp32 into bf16 hi (RNE) + lo (RNE of remainder)
__device__ __forceinline__ void split8(float4 a, float4 b, bf16x8& hi, bf16x8& lo) {
  float f[8] = {a.x, a.y, a.z, a.w, b.x, b.y, b.z, b.w};
  unsigned short h8[8], l8[8];
#pragma unroll
  for (int e = 0; e < 8; ++e) {
    const unsigned short hh = f2bf(f[e]);
    h8[e] = hh;
    l8[e] = f2bf(f[e] - bf2f(hh));
  }
  hi = *(bf16x8*)h8;
  lo = *(bf16x8*)l8;
}

// ------------------------------------------------------------------
// Pack concatenated weights [Wh | Wx] (both [4096][*] fp32) into
// fragment-major bf16 hi/lo with gate-interleaved n-permutation:
// srow(n) = (n&3)*1024 + (n>>6)*16 + ((n>>2)&15)
// pk[((nt*KS + ks)*2 + hilo)*512 + l*8 + e] =
//      src[srow(nt*16+(l&15))][ks*32 + (l>>4)*8 + e]
// ------------------------------------------------------------------
__global__ __launch_bounds__(256)
void pack_w2(const float* __restrict__ Wh, const float* __restrict__ Wx,
             unsigned short* __restrict__ pk, int Kh, int Kx) {
  const int KS = (Kh + Kx) >> 5;
  const int idx = blockIdx.x * 256 + threadIdx.x;
  const int total = 256 * KS * 64;
  if (idx >= total) return;
  const int l = idx & 63;
  const int t2 = idx >> 6;
  const int ks = t2 % KS;
  const int nt = t2 / KS;
  const int n = (nt << 4) + (l & 15);
  const int srow = ((n & 3) << 10) + ((n >> 6) << 4) + ((n >> 2) & 15);
  const int col = (ks << 5) + ((l >> 4) << 3);
  const float* src = (col < Kh) ? (Wh + (size_t)srow * Kh + col)
                                : (Wx + (size_t)srow * Kx + (col - Kh));
  unsigned short hi[8], lo[8];
#pragma unroll
  for (int e = 0; e < 8; ++e) {
    const float v = src[e];
    const unsigned short h = f2bf(v);
    hi[e] = h;
    lo[e] = f2bf(v - bf2f(h));
  }
  const size_t base = (((size_t)nt * KS + ks) * 2) * 512 + (size_t)l * 8;
  *(uint4*)(pk + base) = *(const uint4*)hi;
  *(uint4*)(pk + base + 512) = *(const uint4*)lo;
}

// ------------------------------------------------------------------
// Layer-0 step: gates = [h0_prev | x_t] @ [whh0|wih0]^T + bias; cell; h0_out.
// Grid 128 WGs x 512 thr: WG = (jg = bid&63 -> 16 j, all 4 gates; bh = bid>>6 -> 64 b).
// Wave: mh = wid&1 (32-row half), ng = wid>>1 (16-col group); 2 row-tiles (mt).
// h bufs are [128][1024] bf16 hi/lo. x fp32 [b][t][d], converted in-register.
// ------------------------------------------------------------------
__global__ __launch_bounds__(512)
void step_l0(const unsigned short* __restrict__ p_hi, const unsigned short* __restrict__ p_lo,
             const float* __restrict__ xt,
             unsigned short* __restrict__ n_hi, unsigned short* __restrict__ n_lo,
             const unsigned short* __restrict__ pk,
             const float* __restrict__ b0v, const float* __restrict__ b1v,
             float* __restrict__ cbuf) {
  const int tid = threadIdx.x;
  const int wid = tid >> 6, l = tid & 63;
  const int mh = wid & 1, ng = wid >> 1;
  const int jg = blockIdx.x & 63, bh = blockIdx.x >> 6;
  const int l15 = l & 15, l4 = l >> 4;
  const int nl = (ng << 4) + l15;
  const int rowb = (bh << 6) + (mh << 5) + l15;

  f32x4 acc0 = (f32x4)(0.f), acc1 = (f32x4)(0.f);

  const int nt = (jg << 2) + ng;
  const unsigned short* pkb = pk + (size_t)nt * 48 * 1024 + (size_t)l * 8;
  const unsigned short* ph = p_hi + (size_t)rowb * HH + (l4 << 3);
  const unsigned short* pl = p_lo + (size_t)rowb * HH + (l4 << 3);

#pragma unroll 4
  for (int ks = 0; ks < 32; ++ks) {
    const bf16x8 wh = *(const bf16x8*)(pkb + ks * 1024);
    const bf16x8 wl = *(const bf16x8*)(pkb + ks * 1024 + 512);
    const int ko = ks << 5;
    const bf16x8 ah0 = *(const bf16x8*)(ph + ko);
    const bf16x8 al0 = *(const bf16x8*)(pl + ko);
    const bf16x8 ah1 = *(const bf16x8*)(ph + 16 * HH + ko);
    const bf16x8 al1 = *(const bf16x8*)(pl + 16 * HH + ko);
    acc0 = __builtin_amdgcn_mfma_f32_16x16x32_bf16(ah0, wh, acc0, 0, 0, 0);
    acc0 = __builtin_amdgcn_mfma_f32_16x16x32_bf16(ah0, wl, acc0, 0, 0, 0);
    acc0 = __builtin_amdgcn_mfma_f32_16x16x32_bf16(al0, wh, acc0, 0, 0, 0);
    acc1 = __builtin_amdgcn_mfma_f32_16x16x32_bf16(ah1, wh, acc1, 0, 0, 0);
    acc1 = __builtin_amdgcn_mfma_f32_16x16x32_bf16(ah1, wl, acc1, 0, 0, 0);
    acc1 = __builtin_amdgcn_mfma_f32_16x16x32_bf16(al1, wh, acc1, 0, 0, 0);
  }

  const float* xp = xt + (size_t)rowb * XROW + (l4 << 3);
#pragma unroll 2
  for (int ks = 32; ks < 48; ++ks) {
    const bf16x8 wh = *(const bf16x8*)(pkb + ks * 1024);
    const bf16x8 wl = *(const bf16x8*)(pkb + ks * 1024 + 512);
    const int xo = (ks - 32) << 5;
    float4 f0 = *(const float4*)(xp + xo);
    float4 f1 = *(const float4*)(xp + xo + 4);
    bf16x8 ah, al;
    split8(f0, f1, ah, al);
    acc0 = __builtin_amdgcn_mfma_f32_16x16x32_bf16(ah, wh, acc0, 0, 0, 0);
    acc0 = __builtin_amdgcn_mfma_f32_16x16x32_bf16(ah, wl, acc0, 0, 0, 0);
    acc0 = __builtin_amdgcn_mfma_f32_16x16x32_bf16(al, wh, acc0, 0, 0, 0);
    f0 = *(const float4*)(xp + (size_t)16 * XROW + xo);
    f1 = *(const float4*)(xp + (size_t)16 * XROW + xo + 4);
    split8(f0, f1, ah, al);
    acc1 = __builtin_amdgcn_mfma_f32_16x16x32_bf16(ah, wh, acc1, 0, 0, 0);
    acc1 = __builtin_amdgcn_mfma_f32_16x16x32_bf16(ah, wl, acc1, 0, 0, 0);
    acc1 = __builtin_amdgcn_mfma_f32_16x16x32_bf16(al, wh, acc1, 0, 0, 0);
  }

  const int n = (jg << 6) + nl;
  const int srow = ((n & 3) << 10) + ((n >> 6) << 4) + ((n >> 2) & 15);
  const float bn = b0v[srow] + b1v[srow];
  const int g = nl & 3;
  const int j = (jg << 4) + (nl >> 2);
  f32x4 acc[2] = {acc0, acc1};
#pragma unroll
  for (int mt = 0; mt < 2; ++mt) {
#pragma unroll
    for (int r = 0; r < 4; ++r) {
      const float v = acc[mt][r] + bn;
      const float v1 = __shfl_xor(v, 1);
      const float v2 = __shfl_xor(v, 2);
      const float v3 = __shfl_xor(v, 3);
      if (g == 0) {
        const int b = (bh << 6) + (mh << 5) + (mt << 4) + (l4 << 2) + r;
        const float si = sigmoid_fast(v);
        const float sf = sigmoid_fast(v1);
        const float tg = tanh_fast(v2);
        const float so = sigmoid_fast(v3);
        const size_t ci = (size_t)b * HH + j;
        const float cn = sf * cbuf[ci] + si * tg;
        cbuf[ci] = cn;
        const float h = so * tanh_fast(cn);
        const unsigned short hh = f2bf(h);
        n_hi[(size_t)b * HH + j] = hh;
        n_lo[(size_t)b * HH + j] = f2bf(h - bf2f(hh));
      }
    }
  }
}

// ------------------------------------------------------------------
// Layer-1 step: gates = [h1_prev | h0_t] @ [whh1|wih1]^T + bias; cell; h1_out.
// ------------------------------------------------------------------
__global__ __launch_bounds__(512)
void step_l1(const unsigned short* __restrict__ p_hi, const unsigned short* __restrict__ p_lo,
             const unsigned short* __restrict__ q_hi, const unsigned short* __restrict__ q_lo,
             unsigned short* __restrict__ n_hi, unsigned short* __restrict__ n_lo,
             const unsigned short* __restrict__ pk,
             const float* __restrict__ b0v, const float* __restrict__ b1v,
             float* __restrict__ cbuf) {
  const int tid = threadIdx.x;
  const int wid = tid >> 6, l = tid & 63;
  const int mh = wid & 1, ng = wid >> 1;
  const int jg = blockIdx.x & 63, bh = blockIdx.x >> 6;
  const int l15 = l & 15, l4 = l >> 4;
  const int nl = (ng << 4) + l15;
  const int rowb = (bh << 6) + (mh << 5) + l15;

  f32x4 acc0 = (f32x4)(0.f), acc1 = (f32x4)(0.f);

  const int nt = (jg << 2) + ng;
  const unsigned short* pkb = pk + (size_t)nt * 64 * 1024 + (size_t)l * 8;
  const unsigned short* ph = p_hi + (size_t)rowb * HH + (l4 << 3);
  const unsigned short* pl = p_lo + (size_t)rowb * HH + (l4 << 3);
  const unsigned short* qh = q_hi + (size_t)rowb * HH + (l4 << 3);
  const unsigned short* ql = q_lo + (size_t)rowb * HH + (l4 << 3);

#pragma unroll 4
  for (int ks = 0; ks < 32; ++ks) {
    const bf16x8 wh = *(const bf16x8*)(pkb + ks * 1024);
    const bf16x8 wl = *(const bf16x8*)(pkb + ks * 1024 + 512);
    const int ko = ks << 5;
    const bf16x8 ah0 = *(const bf16x8*)(ph + ko);
    const bf16x8 al0 = *(const bf16x8*)(pl + ko);
    const bf16x8 ah1 = *(const bf16x8*)(ph + 16 * HH + ko);
    const bf16x8 al1 = *(const bf16x8*)(pl + 16 * HH + ko);
    acc0 = __builtin_amdgcn_mfma_f32_16x16x32_bf16(ah0, wh, acc0, 0, 0, 0);
    acc0 = __builtin_amdgcn_mfma_f32_16x16x32_bf16(ah0, wl, acc0, 0, 0, 0);
    acc0 = __builtin_amdgcn_mfma_f32_16x16x32_bf16(al0, wh, acc0, 0, 0, 0);
    acc1 = __builtin_amdgcn_mfma_f32_16x16x32_bf16(ah1, wh, acc1, 0, 0, 0);
    acc1 = __builtin_amdgcn_mfma_f32_16x16x32_bf16(ah1, wl, acc1, 0, 0, 0);
    acc1 = __builtin_amdgcn_mfma_f32_16x16x32_bf16(al1, wh, acc1, 0, 0, 0);
  }
#pragma unroll 4
  for (int ks = 32; ks < 64; ++ks) {
    const bf16x8 wh = *(const bf16x8*)(pkb + ks * 1024);
    const bf16x8 wl = *(const bf16x8*)(pkb + ks * 1024 + 512);
    const int ko = (ks - 32) << 5;
    const bf16x8 ah0 = *(const bf16x8*)(qh + ko);
    const bf16x8 al0 = *(const bf16x8*)(ql + ko);
    const bf16x8 ah1 = *(const bf16x8*)(qh + 16 * HH + ko);
    const bf16x8 al1 = *(const bf16x8*)(ql + 16 * HH + ko);
    acc0 = __builtin_amdgcn_mfma_f32_16x16x32_bf16(ah0, wh, acc0, 0, 0, 0);
    acc0 = __builtin_amdgcn_mfma_f32_16x16x32_bf16(ah0, wl, acc0, 0, 0, 0);
    acc0 = __builtin_amdgcn_mfma_f32_16x16x32_bf16(al0, wh, acc0, 0, 0, 0);
    acc1 = __builtin_amdgcn_mfma_f32_16x16x32_bf16(ah1, wh, acc1, 0, 0, 0);
    acc1 = __builtin_amdgcn_mfma_f32_16x16x32_bf16(ah1, wl, acc1, 0, 0, 0);
    acc1 = __builtin_amdgcn_mfma_f32_16x16x32_bf16(al1, wh, acc1, 0, 0, 0);
  }

  const int n = (jg << 6) + nl;
  const int srow = ((n & 3) << 10) + ((n >> 6) << 4) + ((n >> 2) & 15);
  const float bn = b0v[srow] + b1v[srow];
  const int g = nl & 3;
  const int j = (jg << 4) + (nl >> 2);
  f32x4 acc[2] = {acc0, acc1};
#pragma unroll
  for (int mt = 0; mt < 2; ++mt) {
#pragma unroll
    for (int r = 0; r < 4; ++r) {
      const float v = acc[mt][r] + bn;
      const float v1 = __shfl_xor(v, 1);
      const float v2 = __shfl_xor(v, 2);
      const float v3 = __shfl_xor(v, 3);
      if (g == 0) {
        const int b = (bh << 6) + (mh << 5) + (mt << 4) + (l4 << 2) + r;
        const float si = sigmoid_fast(v);
        const float sf = sigmoid_fast(v1);
        const float tg = tanh_fast(v2);
        const float so = sigmoid_fast(v3);
        const size_t ci = (size_t)b * HH + j;
        const float cn = sf * cbuf[ci] + si * tg;
        cbuf[ci] = cn;
        const float h = so * tanh_fast(cn);
        const unsigned short hh = f2bf(h);
        n_hi[(size_t)b * HH + j] = hh;
        n_lo[(size_t)b * HH + j] = f2bf(h - bf2f(hh));
      }
    }
  }
}

// ------------------------------------------------------------------
// FC from hi/lo h: out[b][n] = (hi+lo)[b] . fc_w[n] + fc_b[n]. One wave/output.
// ------------------------------------------------------------------
__global__ __launch_bounds__(256)
void fc_hilo(const unsigned short* __restrict__ hhi, const unsigned short* __restrict__ hlo,
             const float* __restrict__ fcw, const float* __restrict__ fcb,
             float* __restrict__ out) {
  const int gw = (int)((blockIdx.x * 256 + threadIdx.x) >> 6);
  const int lane = threadIdx.x & 63;
  const int b = gw / CO;
  const int n = gw - b * CO;
  const unsigned short* hp = hhi + (size_t)b * HH;
  const unsigned short* lp = hlo + (size_t)b * HH;
  const float* wp = fcw + (size_t)n * HH;
  float s = 0.f;
  for (int k = lane; k < HH; k += 64) s += (bf2f(hp[k]) + bf2f(lp[k])) * wp[k];
#pragma unroll
  for (int off = 32; off; off >>= 1) s += __shfl_down(s, off);
  if (lane == 0) out[b * CO + n] = s + fcb[n];
}

// ==================================================================
// Fallback fp32 path (round-2, used only if ws_size is too small)
// ==================================================================
__global__ __launch_bounds__(256)
void gemm_bias(const float* __restrict__ A, long long sOut, long long sIn, int lt,
               const float* __restrict__ W,
               const float* __restrict__ b0, const float* __restrict__ b1,
               float* __restrict__ C, int N, int K) {
  __shared__ float as[16][64];
  __shared__ float wsh[16][64];
  const int tid = threadIdx.x;
  const int bm = blockIdx.y << 6;
  const int bn = blockIdx.x << 6;
  const int tr = (tid >> 4) << 2;
  const int tc = (tid & 15) << 2;
  const int lrow = tid >> 2;
  const int lk4 = (tid & 3) << 2;
  const int msk = (1 << lt) - 1;
  const int r = bm + lrow;
  const float* ap = A + (size_t)(r >> lt) * sOut + (size_t)(r & msk) * sIn + lk4;
  const float* wp = W + (size_t)(bn + lrow) * K + lk4;
  float acc[4][4] = {};
  for (int k0 = 0; k0 < K; k0 += 16) {
    const float4 av = *(const float4*)(ap + k0);
    const float4 wv = *(const float4*)(wp + k0);
    __syncthreads();
    as[lk4 + 0][lrow] = av.x; as[lk4 + 1][lrow] = av.y;
    as[lk4 + 2][lrow] = av.z; as[lk4 + 3][lrow] = av.w;
    wsh[lk4 + 0][lrow] = wv.x; wsh[lk4 + 1][lrow] = wv.y;
    wsh[lk4 + 2][lrow] = wv.z; wsh[lk4 + 3][lrow] = wv.w;
    __syncthreads();
#pragma unroll
    for (int k = 0; k < 16; ++k) {
      const float4 a = *(const float4*)&as[k][tr];
      const float4 b = *(const float4*)&wsh[k][tc];
      acc[0][0] += a.x * b.x; acc[0][1] += a.x * b.y; acc[0][2] += a.x * b.z; acc[0][3] += a.x * b.w;
      acc[1][0] += a.y * b.x; acc[1][1] += a.y * b.y; acc[1][2] += a.y * b.z; acc[1][3] += a.y * b.w;
      acc[2][0] += a.z * b.x; acc[2][1] += a.z * b.y; acc[2][2] += a.z * b.z; acc[2][3] += a.z * b.w;
      acc[3][0] += a.w * b.x; acc[3][1] += a.w * b.y; acc[3][2] += a.w * b.z; acc[3][3] += a.w * b.w;
    }
  }
  const float* bp0 = b0 + bn + tc;
  const float* bp1 = b1 + bn + tc;
#pragma unroll
  for (int i = 0; i < 4; ++i) {
    float* cp = C + (size_t)(bm + tr + i) * N + bn + tc;
#pragma unroll
    for (int j = 0; j < 4; ++j) cp[j] = acc[i][j] + bp0[j] + bp1[j];
  }
}

__global__ __launch_bounds__(256)
void lstm_step(const float* __restrict__ gx, long long gxstride,
               const float* __restrict__ whh,
               const float* __restrict__ hprev, long long pstride,
               float* __restrict__ hnext, long long nstride,
               float* __restrict__ cbuf) {
  __shared__ float hs[32][16];
  __shared__ float wsm[32][4][32];
  const int tid = threadIdx.x;
  const int jt = blockIdx.x << 5;
  const int bm = blockIdx.y << 4;
  const int col = tid & 31;
  const int rp = (tid >> 5) << 1;
  const int hr = tid >> 4;
  const int hk = (tid & 15) << 1;
  const int wrow = tid & 127;
  const int wg = wrow >> 5;
  const int wc = wrow & 31;
  const int wk = (tid >> 7) << 4;
  const float* wbase = whh + (size_t)(wg * HH + jt + wc) * HH + wk;
  const float* hbase = hprev + (size_t)(bm + hr) * pstride + hk;

  float acc[4][2] = {};
  for (int k0 = 0; k0 < HH; k0 += 32) {
    const float2 hv = *(const float2*)(hbase + k0);
    const float4 wv0 = *(const float4*)(wbase + k0);
    const float4 wv1 = *(const float4*)(wbase + k0 + 4);
    const float4 wv2 = *(const float4*)(wbase + k0 + 8);
    const float4 wv3 = *(const float4*)(wbase + k0 + 12);
    __syncthreads();
    hs[hk][hr] = hv.x; hs[hk + 1][hr] = hv.y;
    {
      const float wvv[16] = {wv0.x, wv0.y, wv0.z, wv0.w, wv1.x, wv1.y, wv1.z, wv1.w,
                             wv2.x, wv2.y, wv2.z, wv2.w, wv3.x, wv3.y, wv3.z, wv3.w};
#pragma unroll
      for (int i = 0; i < 16; ++i) wsm[wk + i][wg][wc] = wvv[i];
    }
    __syncthreads();
#pragma unroll
    for (int k = 0; k < 32; ++k) {
      const float2 a = *(const float2*)&hs[k][rp];
      const float wi = wsm[k][0][col];
      const float wf = wsm[k][1][col];
      const float wg_ = wsm[k][2][col];
      const float wo = wsm[k][3][col];
      acc[0][0] += a.x * wi;  acc[0][1] += a.y * wi;
      acc[1][0] += a.x * wf;  acc[1][1] += a.y * wf;
      acc[2][0] += a.x * wg_; acc[2][1] += a.y * wg_;
      acc[3][0] += a.x * wo;  acc[3][1] += a.y * wo;
    }
  }
#pragma unroll
  for (int rr = 0; rr < 2; ++rr) {
    const int b = bm + rp + rr;
    const int j = jt + col;
    const size_t gxo = (size_t)b * gxstride + j;
    const float gi = acc[0][rr] + gx[gxo];
    const float gf = acc[1][rr] + gx[gxo + HH];
    const float gg = acc[2][rr] + gx[gxo + 2 * HH];
    const float go = acc[3][rr] + gx[gxo + 3 * HH];
    const float si = 1.f / (1.f + expf(-gi));
    const float sf = 1.f / (1.f + expf(-gf));
    const float so = 1.f / (1.f + expf(-go));
    const size_t cidx = (size_t)b * HH + j;
    const float cn = sf * cbuf[cidx] + si * tanhf(gg);
    cbuf[cidx] = cn;
    hnext[(size_t)b * nstride + j] = so * tanhf(cn);
  }
}

__global__ __launch_bounds__(256)
void fc_kernel(const float* __restrict__ hlast, const float* __restrict__ fcw,
               const float* __restrict__ fcb, float* __restrict__ out) {
  const int gw = (int)((blockIdx.x * 256 + threadIdx.x) >> 6);
  const int lane = threadIdx.x & 63;
  const int b = gw / CO;
  const int n = gw - b * CO;
  const float* hp = hlast + (size_t)b * HH;
  const float* wp = fcw + (size_t)n * HH;
  float s = 0.f;
  for (int k = lane; k < HH; k += 64) s += hp[k] * wp[k];
#pragma unroll
  for (int off = 32; off; off >>= 1) s += __shfl_down(s, off);
  if (lane == 0) out[b * CO + n] = s + fcb[n];
}

// ==================================================================
extern "C" void kernel_launch(void* const* d_in, const int* in_sizes, int n_in,
                              void* d_out, int out_size, void* d_ws, size_t ws_size,
                              hipStream_t stream) {
  const float* x    = (const float*)d_in[0];
  const float* wih0 = (const float*)d_in[1];
  const float* whh0 = (const float*)d_in[2];
  const float* bih0 = (const float*)d_in[3];
  const float* bhh0 = (const float*)d_in[4];
  const float* wih1 = (const float*)d_in[5];
  const float* whh1 = (const float*)d_in[6];
  const float* bih1 = (const float*)d_in[7];
  const float* bhh1 = (const float*)d_in[8];
  const float* fcw  = (const float*)d_in[9];
  const float* fcb  = (const float*)d_in[10];
  float* out = (float*)d_out;

  // ---- MFMA-path workspace ----
  const size_t pk0B = (size_t)256 * 48 * 1024 * 2;   // 25,165,824 B
  const size_t pk1B = (size_t)256 * 64 * 1024 * 2;   // 33,554,432 B
  const size_t hB   = (size_t)BB * HH * 2;           // 262,144 B (one hi or lo buf)
  const size_t cB   = (size_t)BB * HH * 4;           // 524,288 B
  // fixed: pk0 + pk1 + h1a(hi,lo) + zero-block[c0,c1,h1b_hi,h1b_lo]
  const size_t fixedB = pk0B + pk1B + 2 * hB + (2 * cB + 2 * hB);

  int Tc = 16;
  while (Tc > 1 && fixedB + (size_t)(Tc + 1) * 2 * hB > ws_size) Tc >>= 1;

  if (fixedB + (size_t)(Tc + 1) * 2 * hB <= ws_size) {
    char* p = (char*)d_ws;
    unsigned short* pk0 = (unsigned short*)p; p += pk0B;
    unsigned short* pk1 = (unsigned short*)p; p += pk1B;
    unsigned short* h1a_hi = (unsigned short*)p; p += hB;
    unsigned short* h1a_lo = (unsigned short*)p; p += hB;
    char* zblock = p;                      // c0, c1, h1b_hi, h1b_lo (contiguous)
    float* c0 = (float*)p; p += cB;
    float* c1 = (float*)p; p += cB;
    unsigned short* h1b_hi = (unsigned short*)p; p += hB;
    unsigned short* h1b_lo = (unsigned short*)p; p += hB;
    unsigned short* ring = (unsigned short*)p;   // (Tc+1) slots of [hi|lo]
    const size_t slotE = 2 * (size_t)BB * HH;    // elements per slot (hi+lo)

    hipMemsetAsync(zblock, 0, 2 * cB + 2 * hB, stream);
    hipMemsetAsync(ring, 0, 2 * hB, stream);     // slot 0 = h0_{-1} = 0

    pack_w2<<<dim3((256 * 48 * 64) / 256), 256, 0, stream>>>(whh0, wih0, pk0, HH, DD);
    pack_w2<<<dim3((256 * 64 * 64) / 256), 256, 0, stream>>>(whh1, wih1, pk1, HH, HH);

    const int RS = Tc + 1;
    int phase = 0;
    for (int ci = 0; ci < TT / Tc; ++ci) {
      const int t0 = ci * Tc;
      // layer-0 sub-loop (pk0 stays L2-warm within the chunk)
      for (int tl = 0; tl < Tc; ++tl) {
        const int t = t0 + tl;
        const int sp = (phase + tl) % RS;
        const int sn = (phase + tl + 1) % RS;
        step_l0<<<dim3(128), 512, 0, stream>>>(
            ring + (size_t)sp * slotE, ring + (size_t)sp * slotE + (size_t)BB * HH,
            x + (size_t)t * DD,
            ring + (size_t)sn * slotE, ring + (size_t)sn * slotE + (size_t)BB * HH,
            pk0, bih0, bhh0, c0);
      }
      // layer-1 sub-loop (pk1 stays L2-warm within the chunk)
      for (int tl = 0; tl < Tc; ++tl) {
        const int t = t0 + tl;
        const int sn = (phase + tl + 1) % RS;
        const unsigned short* php = (t & 1) ? h1a_hi : h1b_hi;  // h1_{t-1}
        const unsigned short* plp = (t & 1) ? h1a_lo : h1b_lo;
        unsigned short* nhp = (t & 1) ? h1b_hi : h1a_hi;        // h1_t
        unsigned short* nlp = (t & 1) ? h1b_lo : h1a_lo;
        step_l1<<<dim3(128), 512, 0, stream>>>(
            php, plp,
            ring + (size_t)sn * slotE, ring + (size_t)sn * slotE + (size_t)BB * HH,
            nhp, nlp, pk1, bih1, bhh1, c1);
      }
      phase = (phase + Tc) % RS;
    }

    // t = 255 (odd) wrote h1b
    fc_hilo<<<dim3((BB * CO * 64) / 256), 256, 0, stream>>>(h1b_hi, h1b_lo, fcw, fcb, out);
    return;
  }

  // ---------------- fallback fp32 path ----------------
  {
    int Tc2 = 64, lt2 = 6;
    while (Tc2 > 1) {
      size_t need = ((size_t)655360 * (size_t)Tc2 + 4u * 131072u + 1024u) * 4u;
      if (need <= ws_size) break;
      Tc2 >>= 1; --lt2;
    }
    float* ws  = (float*)d_ws;
    float* gxc = ws;
    float* hc  = gxc + (size_t)BB * Tc2 * G4H;
    float* c0  = hc + (size_t)BB * Tc2 * HH;
    float* c1  = c0 + (size_t)BB * HH;
    float* h2a = c1 + (size_t)BB * HH;
    float* h2b = h2a + (size_t)BB * HH;
    float* zb  = h2b + (size_t)BB * HH;

    hipMemsetAsync(zb, 0, HH * sizeof(float), stream);
    hipMemsetAsync(c0, 0, (size_t)BB * HH * sizeof(float), stream);
    hipMemsetAsync(c1, 0, (size_t)BB * HH * sizeof(float), stream);

    const dim3 gGemm(G4H / 64, (BB * Tc2) / 64);
    const dim3 gStep(HH / 32, BB / 16);
    const long long gxs = (long long)Tc2 * G4H;
    const long long hcs = (long long)Tc2 * HH;

    const int nChunks = TT / Tc2;
    for (int ci = 0; ci < nChunks; ++ci) {
      const int t0 = ci * Tc2;
      gemm_bias<<<gGemm, 256, 0, stream>>>(x + (size_t)t0 * DD, (long long)TT * DD,
                                           (long long)DD, lt2, wih0, bih0, bhh0,
                                           gxc, G4H, DD);
      for (int tl = 0; tl < Tc2; ++tl) {
        const int t = t0 + tl;
        const float* hprev;
        long long ps;
        if (t == 0) { hprev = zb; ps = 0; }
        else {
          const int ptl = (tl == 0) ? (Tc2 - 1) : (tl - 1);
          hprev = hc + (size_t)ptl * HH; ps = hcs;
        }
        lstm_step<<<gStep, 256, 0, stream>>>(gxc + (size_t)tl * G4H, gxs, whh0,
                                             hprev, ps, hc + (size_t)tl * HH, hcs, c0);
      }
      gemm_bias<<<gGemm, 256, 0, stream>>>(hc, hcs, (long long)HH, lt2,
                                           wih1, bih1, bhh1, gxc, G4H, HH);
      for (int tl = 0; tl < Tc2; ++tl) {
        const int t = t0 + tl;
        const float* hprev;
        long long ps;
        if (t == 0) { hprev = zb; ps = 0; }
        else { hprev = ((t - 1) & 1) ? h2b : h2a; ps = HH; }
        float* hnext = (t & 1) ? h2b : h2a;
        lstm_step<<<gStep, 256, 0, stream>>>(gxc + (size_t)tl * G4H, gxs, whh1,
                                             hprev, ps, hnext, HH, c1);
      }
    }
    fc_kernel<<<dim3((BB * CO * 64) / 256), 256, 0, stream>>>(h2b, fcw, fcb, out);
  }
}

// Round 5
// 18854.814 us; speedup vs baseline: 2.2152x; 1.7897x over previous
//
#include <hip/hip_runtime.h>
#include <math.h>

#define BB 128
#define TT 256
#define DD 512
#define HH 1024
#define G4H 4096
#define CO 7
#define XROW (TT * DD)      // x row stride per batch (fp32 elements)
#define LOOFF (BB * HH)     // offset of lo-plane within an h slot (elements)

typedef __attribute__((ext_vector_type(8))) short bf16x8;
typedef __attribute__((ext_vector_type(4))) float f32x4;

__device__ __forceinline__ unsigned short f2bf(float f) {
  unsigned int u = __float_as_uint(f);
  unsigned int r = (u + 0x7fffu + ((u >> 16) & 1u)) >> 16;
  return (unsigned short)r;
}
__device__ __forceinline__ float bf2f(unsigned short h) {
  return __uint_as_float(((unsigned int)h) << 16);
}
__device__ __forceinline__ float tanh_fast(float x) {
  x = fminf(fmaxf(x, -15.f), 15.f);
  const float e = __expf(2.f * x);
  return (e - 1.f) / (e + 1.f);
}
__device__ __forceinline__ float sigmoid_fast(float x) {
  return 1.f / (1.f + __expf(-x));
}
__device__ __forceinline__ void split8(float4 a, float4 b, bf16x8& hi, bf16x8& lo) {
  float f[8] = {a.x, a.y, a.z, a.w, b.x, b.y, b.z, b.w};
  unsigned short h8[8], l8[8];
#pragma unroll
  for (int e = 0; e < 8; ++e) {
    const unsigned short hh = f2bf(f[e]);
    h8[e] = hh;
    l8[e] = f2bf(f[e] - bf2f(hh));
  }
  hi = *(bf16x8*)h8;
  lo = *(bf16x8*)l8;
}

// ------------------------------------------------------------------
// Pack concatenated weights [Wh | Wx] into fragment-major bf16 hi/lo,
// gate-interleaved n-permutation: srow(n) = (n&3)*1024 + (n>>6)*16 + ((n>>2)&15)
// pk[((nt*KS + ks)*2 + hilo)*512 + l*8 + e] = src[srow(nt*16+(l&15))][ks*32+(l>>4)*8+e]
// ------------------------------------------------------------------
__global__ __launch_bounds__(256)
void pack_w2(const float* __restrict__ Wh, const float* __restrict__ Wx,
             unsigned short* __restrict__ pk, int Kh, int Kx) {
  const int KS = (Kh + Kx) >> 5;
  const int idx = blockIdx.x * 256 + threadIdx.x;
  const int total = 256 * KS * 64;
  if (idx >= total) return;
  const int l = idx & 63;
  const int t2 = idx >> 6;
  const int ks = t2 % KS;
  const int nt = t2 / KS;
  const int n = (nt << 4) + (l & 15);
  const int srow = ((n & 3) << 10) + ((n >> 6) << 4) + ((n >> 2) & 15);
  const int col = (ks << 5) + ((l >> 4) << 3);
  const float* src = (col < Kh) ? (Wh + (size_t)srow * Kh + col)
                                : (Wx + (size_t)srow * Kx + (col - Kh));
  unsigned short hi[8], lo[8];
#pragma unroll
  for (int e = 0; e < 8; ++e) {
    const float v = src[e];
    const unsigned short h = f2bf(v);
    hi[e] = h;
    lo[e] = f2bf(v - bf2f(h));
  }
  const size_t base = (((size_t)nt * KS + ks) * 2) * 512 + (size_t)l * 8;
  *(uint4*)(pk + base) = *(const uint4*)hi;
  *(uint4*)(pk + base + 512) = *(const uint4*)lo;
}

// 4-ks block of bf16x3 MFMA from LDS weights + bf16 hi/lo A operand
__device__ __forceinline__ void blk_bf16(const unsigned short* wb, const unsigned short* ap,
                                         f32x4& acc0, f32x4& acc1) {
#pragma unroll
  for (int ksl = 0; ksl < 4; ++ksl) {
    const bf16x8 wh = *(const bf16x8*)(wb + ksl * 1024);
    const bf16x8 wl = *(const bf16x8*)(wb + ksl * 1024 + 512);
    const unsigned short* p = ap + (ksl << 5);
    const bf16x8 ah0 = *(const bf16x8*)p;
    const bf16x8 al0 = *(const bf16x8*)(p + LOOFF);
    const bf16x8 ah1 = *(const bf16x8*)(p + 16 * HH);
    const bf16x8 al1 = *(const bf16x8*)(p + LOOFF + 16 * HH);
    acc0 = __builtin_amdgcn_mfma_f32_16x16x32_bf16(ah0, wh, acc0, 0, 0, 0);
    acc0 = __builtin_amdgcn_mfma_f32_16x16x32_bf16(ah0, wl, acc0, 0, 0, 0);
    acc0 = __builtin_amdgcn_mfma_f32_16x16x32_bf16(al0, wh, acc0, 0, 0, 0);
    acc1 = __builtin_amdgcn_mfma_f32_16x16x32_bf16(ah1, wh, acc1, 0, 0, 0);
    acc1 = __builtin_amdgcn_mfma_f32_16x16x32_bf16(ah1, wl, acc1, 0, 0, 0);
    acc1 = __builtin_amdgcn_mfma_f32_16x16x32_bf16(al1, wh, acc1, 0, 0, 0);
  }
}

// 4-ks block with fp32 A operand (x), converted to hi/lo in-register
__device__ __forceinline__ void blk_x(const unsigned short* wb, const float* xp,
                                      f32x4& acc0, f32x4& acc1) {
#pragma unroll
  for (int ksl = 0; ksl < 4; ++ksl) {
    const bf16x8 wh = *(const bf16x8*)(wb + ksl * 1024);
    const bf16x8 wl = *(const bf16x8*)(wb + ksl * 1024 + 512);
    const float* p = xp + (ksl << 5);
    bf16x8 ah, al;
    split8(*(const float4*)p, *(const float4*)(p + 4), ah, al);
    acc0 = __builtin_amdgcn_mfma_f32_16x16x32_bf16(ah, wh, acc0, 0, 0, 0);
    acc0 = __builtin_amdgcn_mfma_f32_16x16x32_bf16(ah, wl, acc0, 0, 0, 0);
    acc0 = __builtin_amdgcn_mfma_f32_16x16x32_bf16(al, wh, acc0, 0, 0, 0);
    split8(*(const float4*)(p + 16 * XROW), *(const float4*)(p + 16 * XROW + 4), ah, al);
    acc1 = __builtin_amdgcn_mfma_f32_16x16x32_bf16(ah, wh, acc1, 0, 0, 0);
    acc1 = __builtin_amdgcn_mfma_f32_16x16x32_bf16(ah, wl, acc1, 0, 0, 0);
    acc1 = __builtin_amdgcn_mfma_f32_16x16x32_bf16(al, wh, acc1, 0, 0, 0);
  }
}

// ------------------------------------------------------------------
// Diagonal dual-layer step: WGs 0..127 run layer0 @ t, WGs 128..255 run
// layer1 @ t-1 (independent). 512 thr/WG. Weights LDS-staged, double-buffered.
// h slots: [hi(BB*HH) | lo(BB*HH)] each.
// ------------------------------------------------------------------
__global__ __launch_bounds__(512)
void step_dual(int t,
               const float* __restrict__ x,
               const unsigned short* __restrict__ pk0,
               const unsigned short* __restrict__ pk1,
               unsigned short* __restrict__ h0s0, unsigned short* __restrict__ h0s1,
               unsigned short* __restrict__ h1s0, unsigned short* __restrict__ h1s1,
               const float* __restrict__ bih0, const float* __restrict__ bhh0,
               const float* __restrict__ bih1, const float* __restrict__ bhh1,
               float* __restrict__ c0, float* __restrict__ c1) {
  __shared__ unsigned short lds[2][16384];   // 2 x 32KB: [ntl*4096 + ksl*1024 + hilo*512 + l*8 + e]
  const int bid = blockIdx.x;
  const int layer = bid >> 7;
  if (layer == 0 && t >= TT) return;
  if (layer == 1 && t < 1) return;
  const int lbid = bid & 127;
  const int jg = lbid & 63, bh = lbid >> 6;
  const int tid = threadIdx.x;
  const int wid = tid >> 6, l = tid & 63;
  const int mh = wid & 1, ng = wid >> 1;
  const int l15 = l & 15, l4 = l >> 4;
  const int nl = (ng << 4) + l15;
  const int rowb = (bh << 6) + (mh << 5) + l15;

  // per-layer configuration
  const int KS = layer ? 64 : 48;
  const unsigned short* pk = layer ? pk1 : pk0;
  const unsigned short* a1;       // prev-h of own layer (hi base; lo at +LOOFF)
  const unsigned short* a2;       // layer1: h0[t-1]
  unsigned short* ho;             // output h slot
  float* cb;
  const float* bv0;
  const float* bv1;
  if (layer == 0) {
    a1 = (t & 1) ? h0s0 : h0s1;   // h0[t-1] at slot[(t-1)&1]
    ho = (t & 1) ? h0s1 : h0s0;   // h0[t]   at slot[t&1]
    a2 = a1;                      // unused
    cb = c0; bv0 = bih0; bv1 = bhh0;
  } else {
    const int u = t - 1;
    a1 = (u & 1) ? h1s0 : h1s1;   // h1[u-1] at slot[(u-1)&1]
    ho = (u & 1) ? h1s1 : h1s0;   // h1[u]   at slot[u&1]
    a2 = (t & 1) ? h0s0 : h0s1;   // h0[t-1] at slot[(t-1)&1]
    cb = c1; bv0 = bih1; bv1 = bhh1;
  }

  f32x4 acc0 = (f32x4)(0.f), acc1 = (f32x4)(0.f);

  // A-side base pointers (per-lane)
  const unsigned short* a1p = a1 + (size_t)rowb * HH + (l4 << 3);
  const unsigned short* a2p = a2 + (size_t)rowb * HH + (l4 << 3);
  const float* xp = x + (size_t)t * DD + (size_t)rowb * XROW + (l4 << 3);

  // weight chunk base pointers (per-thread, 16B each)
  const unsigned short* pkc0 = pk + ((size_t)(jg * 4 + 0) * KS) * 1024 + (size_t)tid * 8;
  const unsigned short* pkc1 = pk + ((size_t)(jg * 4 + 1) * KS) * 1024 + (size_t)tid * 8;
  const unsigned short* pkc2 = pk + ((size_t)(jg * 4 + 2) * KS) * 1024 + (size_t)tid * 8;
  const unsigned short* pkc3 = pk + ((size_t)(jg * 4 + 3) * KS) * 1024 + (size_t)tid * 8;

  const unsigned short* wb0 = &lds[0][ng * 4096 + l * 8];
  const unsigned short* wb1 = &lds[1][ng * 4096 + l * 8];
  const int NB = KS >> 2;   // 12 or 16 (even)

#define DO_BLOCK(bb, wb) do {                                               \
    if ((bb) < 8)            blk_bf16((wb), a1p + (bb) * 128, acc0, acc1);  \
    else if (layer == 0)     blk_x   ((wb), xp + ((bb) - 8) * 128, acc0, acc1); \
    else                     blk_bf16((wb), a2p + ((bb) - 8) * 128, acc0, acc1); \
  } while (0)

  uint4 qa0, qa1, qa2, qa3, qb0, qb1, qb2, qb3;
  // prologue: stage block 0 into buf0
  qa0 = *(const uint4*)pkc0; qa1 = *(const uint4*)pkc1;
  qa2 = *(const uint4*)pkc2; qa3 = *(const uint4*)pkc3;
  *(uint4*)&lds[0][0 * 4096 + tid * 8] = qa0;
  *(uint4*)&lds[0][1 * 4096 + tid * 8] = qa1;
  *(uint4*)&lds[0][2 * 4096 + tid * 8] = qa2;
  *(uint4*)&lds[0][3 * 4096 + tid * 8] = qa3;
  __syncthreads();

  for (int b = 0; b < NB; b += 2) {
    // even block (buf0 staged)
    if (b + 1 < NB) {
      qb0 = *(const uint4*)(pkc0 + (size_t)(b + 1) * 4096);
      qb1 = *(const uint4*)(pkc1 + (size_t)(b + 1) * 4096);
      qb2 = *(const uint4*)(pkc2 + (size_t)(b + 1) * 4096);
      qb3 = *(const uint4*)(pkc3 + (size_t)(b + 1) * 4096);
    }
    DO_BLOCK(b, wb0);
    if (b + 1 < NB) {
      *(uint4*)&lds[1][0 * 4096 + tid * 8] = qb0;
      *(uint4*)&lds[1][1 * 4096 + tid * 8] = qb1;
      *(uint4*)&lds[1][2 * 4096 + tid * 8] = qb2;
      *(uint4*)&lds[1][3 * 4096 + tid * 8] = qb3;
    }
    __syncthreads();
    if (b + 1 < NB) {
      // odd block (buf1 staged)
      if (b + 2 < NB) {
        qa0 = *(const uint4*)(pkc0 + (size_t)(b + 2) * 4096);
        qa1 = *(const uint4*)(pkc1 + (size_t)(b + 2) * 4096);
        qa2 = *(const uint4*)(pkc2 + (size_t)(b + 2) * 4096);
        qa3 = *(const uint4*)(pkc3 + (size_t)(b + 2) * 4096);
      }
      DO_BLOCK(b + 1, wb1);
      if (b + 2 < NB) {
        *(uint4*)&lds[0][0 * 4096 + tid * 8] = qa0;
        *(uint4*)&lds[0][1 * 4096 + tid * 8] = qa1;
        *(uint4*)&lds[0][2 * 4096 + tid * 8] = qa2;
        *(uint4*)&lds[0][3 * 4096 + tid * 8] = qa3;
      }
      __syncthreads();
    }
  }
#undef DO_BLOCK

  // epilogue: bias + cell + h store (quad shfl gather: g = nl&3)
  const int n = (jg << 6) + nl;
  const int srow = ((n & 3) << 10) + ((n >> 6) << 4) + ((n >> 2) & 15);
  const float bn = bv0[srow] + bv1[srow];
  const int g = nl & 3;
  const int j = (jg << 4) + (nl >> 2);
  f32x4 accs[2] = {acc0, acc1};
#pragma unroll
  for (int mt = 0; mt < 2; ++mt) {
#pragma unroll
    for (int r = 0; r < 4; ++r) {
      const float v = accs[mt][r] + bn;
      const float v1 = __shfl_xor(v, 1);
      const float v2 = __shfl_xor(v, 2);
      const float v3 = __shfl_xor(v, 3);
      if (g == 0) {
        const int b = (bh << 6) + (mh << 5) + (mt << 4) + (l4 << 2) + r;
        const float si = sigmoid_fast(v);
        const float sf = sigmoid_fast(v1);
        const float tg = tanh_fast(v2);
        const float so = sigmoid_fast(v3);
        const size_t ci = (size_t)b * HH + j;
        const float cn = sf * cb[ci] + si * tg;
        cb[ci] = cn;
        const float h = so * tanh_fast(cn);
        const unsigned short hh = f2bf(h);
        ho[(size_t)b * HH + j] = hh;
        ho[LOOFF + (size_t)b * HH + j] = f2bf(h - bf2f(hh));
      }
    }
  }
}

// ------------------------------------------------------------------
// FC from hi/lo h slot
// ------------------------------------------------------------------
__global__ __launch_bounds__(256)
void fc_hilo(const unsigned short* __restrict__ hhi, const unsigned short* __restrict__ hlo,
             const float* __restrict__ fcw, const float* __restrict__ fcb,
             float* __restrict__ out) {
  const int gw = (int)((blockIdx.x * 256 + threadIdx.x) >> 6);
  const int lane = threadIdx.x & 63;
  const int b = gw / CO;
  const int n = gw - b * CO;
  const unsigned short* hp = hhi + (size_t)b * HH;
  const unsigned short* lp = hlo + (size_t)b * HH;
  const float* wp = fcw + (size_t)n * HH;
  float s = 0.f;
  for (int k = lane; k < HH; k += 64) s += (bf2f(hp[k]) + bf2f(lp[k])) * wp[k];
#pragma unroll
  for (int off = 32; off; off >>= 1) s += __shfl_down(s, off);
  if (lane == 0) out[b * CO + n] = s + fcb[n];
}

// ==================================================================
// Fallback fp32 path (round-2 kernels, used only if ws_size is small)
// ==================================================================
__global__ __launch_bounds__(256)
void gemm_bias(const float* __restrict__ A, long long sOut, long long sIn, int lt,
               const float* __restrict__ W,
               const float* __restrict__ b0, const float* __restrict__ b1,
               float* __restrict__ C, int N, int K) {
  __shared__ float as[16][64];
  __shared__ float wsh[16][64];
  const int tid = threadIdx.x;
  const int bm = blockIdx.y << 6;
  const int bn = blockIdx.x << 6;
  const int tr = (tid >> 4) << 2;
  const int tc = (tid & 15) << 2;
  const int lrow = tid >> 2;
  const int lk4 = (tid & 3) << 2;
  const int msk = (1 << lt) - 1;
  const int r = bm + lrow;
  const float* ap = A + (size_t)(r >> lt) * sOut + (size_t)(r & msk) * sIn + lk4;
  const float* wp = W + (size_t)(bn + lrow) * K + lk4;
  float acc[4][4] = {};
  for (int k0 = 0; k0 < K; k0 += 16) {
    const float4 av = *(const float4*)(ap + k0);
    const float4 wv = *(const float4*)(wp + k0);
    __syncthreads();
    as[lk4 + 0][lrow] = av.x; as[lk4 + 1][lrow] = av.y;
    as[lk4 + 2][lrow] = av.z; as[lk4 + 3][lrow] = av.w;
    wsh[lk4 + 0][lrow] = wv.x; wsh[lk4 + 1][lrow] = wv.y;
    wsh[lk4 + 2][lrow] = wv.z; wsh[lk4 + 3][lrow] = wv.w;
    __syncthreads();
#pragma unroll
    for (int k = 0; k < 16; ++k) {
      const float4 a = *(const float4*)&as[k][tr];
      const float4 b = *(const float4*)&wsh[k][tc];
      acc[0][0] += a.x * b.x; acc[0][1] += a.x * b.y; acc[0][2] += a.x * b.z; acc[0][3] += a.x * b.w;
      acc[1][0] += a.y * b.x; acc[1][1] += a.y * b.y; acc[1][2] += a.y * b.z; acc[1][3] += a.y * b.w;
      acc[2][0] += a.z * b.x; acc[2][1] += a.z * b.y; acc[2][2] += a.z * b.z; acc[2][3] += a.z * b.w;
      acc[3][0] += a.w * b.x; acc[3][1] += a.w * b.y; acc[3][2] += a.w * b.z; acc[3][3] += a.w * b.w;
    }
  }
  const float* bp0 = b0 + bn + tc;
  const float* bp1 = b1 + bn + tc;
#pragma unroll
  for (int i = 0; i < 4; ++i) {
    float* cp = C + (size_t)(bm + tr + i) * N + bn + tc;
#pragma unroll
    for (int j = 0; j < 4; ++j) cp[j] = acc[i][j] + bp0[j] + bp1[j];
  }
}

__global__ __launch_bounds__(256)
void lstm_step(const float* __restrict__ gx, long long gxstride,
               const float* __restrict__ whh,
               const float* __restrict__ hprev, long long pstride,
               float* __restrict__ hnext, long long nstride,
               float* __restrict__ cbuf) {
  __shared__ float hs[32][16];
  __shared__ float wsm[32][4][32];
  const int tid = threadIdx.x;
  const int jt = blockIdx.x << 5;
  const int bm = blockIdx.y << 4;
  const int col = tid & 31;
  const int rp = (tid >> 5) << 1;
  const int hr = tid >> 4;
  const int hk = (tid & 15) << 1;
  const int wrow = tid & 127;
  const int wg = wrow >> 5;
  const int wc = wrow & 31;
  const int wk = (tid >> 7) << 4;
  const float* wbase = whh + (size_t)(wg * HH + jt + wc) * HH + wk;
  const float* hbase = hprev + (size_t)(bm + hr) * pstride + hk;

  float acc[4][2] = {};
  for (int k0 = 0; k0 < HH; k0 += 32) {
    const float2 hv = *(const float2*)(hbase + k0);
    const float4 wv0 = *(const float4*)(wbase + k0);
    const float4 wv1 = *(const float4*)(wbase + k0 + 4);
    const float4 wv2 = *(const float4*)(wbase + k0 + 8);
    const float4 wv3 = *(const float4*)(wbase + k0 + 12);
    __syncthreads();
    hs[hk][hr] = hv.x; hs[hk + 1][hr] = hv.y;
    {
      const float wvv[16] = {wv0.x, wv0.y, wv0.z, wv0.w, wv1.x, wv1.y, wv1.z, wv1.w,
                             wv2.x, wv2.y, wv2.z, wv2.w, wv3.x, wv3.y, wv3.z, wv3.w};
#pragma unroll
      for (int i = 0; i < 16; ++i) wsm[wk + i][wg][wc] = wvv[i];
    }
    __syncthreads();
#pragma unroll
    for (int k = 0; k < 32; ++k) {
      const float2 a = *(const float2*)&hs[k][rp];
      const float wi = wsm[k][0][col];
      const float wf = wsm[k][1][col];
      const float wg_ = wsm[k][2][col];
      const float wo = wsm[k][3][col];
      acc[0][0] += a.x * wi;  acc[0][1] += a.y * wi;
      acc[1][0] += a.x * wf;  acc[1][1] += a.y * wf;
      acc[2][0] += a.x * wg_; acc[2][1] += a.y * wg_;
      acc[3][0] += a.x * wo;  acc[3][1] += a.y * wo;
    }
  }
#pragma unroll
  for (int rr = 0; rr < 2; ++rr) {
    const int b = bm + rp + rr;
    const int j = jt + col;
    const size_t gxo = (size_t)b * gxstride + j;
    const float gi = acc[0][rr] + gx[gxo];
    const float gf = acc[1][rr] + gx[gxo + HH];
    const float gg = acc[2][rr] + gx[gxo + 2 * HH];
    const float go = acc[3][rr] + gx[gxo + 3 * HH];
    const float si = 1.f / (1.f + expf(-gi));
    const float sf = 1.f / (1.f + expf(-gf));
    const float so = 1.f / (1.f + expf(-go));
    const size_t cidx = (size_t)b * HH + j;
    const float cn = sf * cbuf[cidx] + si * tanhf(gg);
    cbuf[cidx] = cn;
    hnext[(size_t)b * nstride + j] = so * tanhf(cn);
  }
}

__global__ __launch_bounds__(256)
void fc_kernel(const float* __restrict__ hlast, const float* __restrict__ fcw,
               const float* __restrict__ fcb, float* __restrict__ out) {
  const int gw = (int)((blockIdx.x * 256 + threadIdx.x) >> 6);
  const int lane = threadIdx.x & 63;
  const int b = gw / CO;
  const int n = gw - b * CO;
  const float* hp = hlast + (size_t)b * HH;
  const float* wp = fcw + (size_t)n * HH;
  float s = 0.f;
  for (int k = lane; k < HH; k += 64) s += hp[k] * wp[k];
#pragma unroll
  for (int off = 32; off; off >>= 1) s += __shfl_down(s, off);
  if (lane == 0) out[b * CO + n] = s + fcb[n];
}

// ==================================================================
extern "C" void kernel_launch(void* const* d_in, const int* in_sizes, int n_in,
                              void* d_out, int out_size, void* d_ws, size_t ws_size,
                              hipStream_t stream) {
  const float* x    = (const float*)d_in[0];
  const float* wih0 = (const float*)d_in[1];
  const float* whh0 = (const float*)d_in[2];
  const float* bih0 = (const float*)d_in[3];
  const float* bhh0 = (const float*)d_in[4];
  const float* wih1 = (const float*)d_in[5];
  const float* whh1 = (const float*)d_in[6];
  const float* bih1 = (const float*)d_in[7];
  const float* bhh1 = (const float*)d_in[8];
  const float* fcw  = (const float*)d_in[9];
  const float* fcb  = (const float*)d_in[10];
  float* out = (float*)d_out;

  // ---- MFMA-path workspace ----
  const size_t pk0B  = (size_t)256 * 48 * 1024 * 2;   // 25,165,824 B
  const size_t pk1B  = (size_t)256 * 64 * 1024 * 2;   // 33,554,432 B
  const size_t slotB = 2 * (size_t)BB * HH * 2;       // 524,288 B (hi+lo)
  const size_t cB    = (size_t)BB * HH * 4;           // 524,288 B
  const size_t needB = pk0B + pk1B + 4 * slotB + 2 * cB;  // 61,865,984 B

  if (needB <= ws_size) {
    char* p = (char*)d_ws;
    unsigned short* pk0  = (unsigned short*)p; p += pk0B;
    unsigned short* pk1  = (unsigned short*)p; p += pk1B;
    unsigned short* h0s0 = (unsigned short*)p; p += slotB;
    unsigned short* h1s0 = (unsigned short*)p; p += slotB;
    char* zblock = p;                         // h0s1, h1s1, c0, c1 (zeroed)
    unsigned short* h0s1 = (unsigned short*)p; p += slotB;
    unsigned short* h1s1 = (unsigned short*)p; p += slotB;
    float* c0 = (float*)p; p += cB;
    float* c1 = (float*)p; p += cB;

    hipMemsetAsync(zblock, 0, 2 * slotB + 2 * cB, stream);

    pack_w2<<<dim3((256 * 48 * 64) / 256), 256, 0, stream>>>(whh0, wih0, pk0, HH, DD);
    pack_w2<<<dim3((256 * 64 * 64) / 256), 256, 0, stream>>>(whh1, wih1, pk1, HH, HH);

    for (int t = 0; t <= TT; ++t) {
      step_dual<<<dim3(256), 512, 0, stream>>>(t, x, pk0, pk1,
                                               h0s0, h0s1, h1s0, h1s1,
                                               bih0, bhh0, bih1, bhh1, c0, c1);
    }

    // final u = 255 (odd) wrote slot[1] = h1s1
    fc_hilo<<<dim3((BB * CO * 64) / 256), 256, 0, stream>>>(h1s1, h1s1 + LOOFF,
                                                            fcw, fcb, out);
    return;
  }

  // ---------------- fallback fp32 path ----------------
  {
    int Tc2 = 64, lt2 = 6;
    while (Tc2 > 1) {
      size_t need = ((size_t)655360 * (size_t)Tc2 + 4u * 131072u + 1024u) * 4u;
      if (need <= ws_size) break;
      Tc2 >>= 1; --lt2;
    }
    float* ws  = (float*)d_ws;
    float* gxc = ws;
    float* hc  = gxc + (size_t)BB * Tc2 * G4H;
    float* c0  = hc + (size_t)BB * Tc2 * HH;
    float* c1  = c0 + (size_t)BB * HH;
    float* h2a = c1 + (size_t)BB * HH;
    float* h2b = h2a + (size_t)BB * HH;
    float* zb  = h2b + (size_t)BB * HH;

    hipMemsetAsync(zb, 0, HH * sizeof(float), stream);
    hipMemsetAsync(c0, 0, (size_t)BB * HH * sizeof(float), stream);
    hipMemsetAsync(c1, 0, (size_t)BB * HH * sizeof(float), stream);

    const dim3 gGemm(G4H / 64, (BB * Tc2) / 64);
    const dim3 gStep(HH / 32, BB / 16);
    const long long gxs = (long long)Tc2 * G4H;
    const long long hcs = (long long)Tc2 * HH;

    const int nChunks = TT / Tc2;
    for (int ci = 0; ci < nChunks; ++ci) {
      const int t0 = ci * Tc2;
      gemm_bias<<<gGemm, 256, 0, stream>>>(x + (size_t)t0 * DD, (long long)TT * DD,
                                           (long long)DD, lt2, wih0, bih0, bhh0,
                                           gxc, G4H, DD);
      for (int tl = 0; tl < Tc2; ++tl) {
        const int t = t0 + tl;
        const float* hprev;
        long long ps;
        if (t == 0) { hprev = zb; ps = 0; }
        else {
          const int ptl = (tl == 0) ? (Tc2 - 1) : (tl - 1);
          hprev = hc + (size_t)ptl * HH; ps = hcs;
        }
        lstm_step<<<gStep, 256, 0, stream>>>(gxc + (size_t)tl * G4H, gxs, whh0,
                                             hprev, ps, hc + (size_t)tl * HH, hcs, c0);
      }
      gemm_bias<<<gGemm, 256, 0, stream>>>(hc, hcs, (long long)HH, lt2,
                                           wih1, bih1, bhh1, gxc, G4H, HH);
      for (int tl = 0; tl < Tc2; ++tl) {
        const int t = t0 + tl;
        const float* hprev;
        long long ps;
        if (t == 0) { hprev = zb; ps = 0; }
        else { hprev = ((t - 1) & 1) ? h2b : h2a; ps = HH; }
        float* hnext = (t & 1) ? h2b : h2a;
        lstm_step<<<gStep, 256, 0, stream>>>(gxc + (size_t)tl * G4H, gxs, whh1,
                                             hprev, ps, hnext, HH, c1);
      }
    }
    fc_kernel<<<dim3((BB * CO * 64) / 256), 256, 0, stream>>>(h2b, fcw, fcb, out);
  }
}

// Round 6
// 6937.745 us; speedup vs baseline: 6.0203x; 2.7177x over previous
//
#include <hip/hip_runtime.h>
#include <math.h>

#define BB 128
#define TT 256
#define DD 512
#define HH 1024
#define G4H 4096
#define CO 7
#define XROW (TT * DD)      // x row stride per batch (fp32 elements)
#define LOOFF (BB * HH)     // offset of lo-plane within an h slot (elements)

typedef __attribute__((ext_vector_type(8))) short bf16x8;
typedef __attribute__((ext_vector_type(4))) float f32x4;

__device__ __forceinline__ unsigned short f2bf(float f) {
  unsigned int u = __float_as_uint(f);
  unsigned int r = (u + 0x7fffu + ((u >> 16) & 1u)) >> 16;
  return (unsigned short)r;
}
__device__ __forceinline__ float bf2f(unsigned short h) {
  return __uint_as_float(((unsigned int)h) << 16);
}
__device__ __forceinline__ float tanh_fast(float x) {
  x = fminf(fmaxf(x, -15.f), 15.f);
  const float e = __expf(2.f * x);
  return (e - 1.f) / (e + 1.f);
}
__device__ __forceinline__ float sigmoid_fast(float x) {
  return 1.f / (1.f + __expf(-x));
}
__device__ __forceinline__ void split8(float4 a, float4 b, bf16x8& hi, bf16x8& lo) {
  float f[8] = {a.x, a.y, a.z, a.w, b.x, b.y, b.z, b.w};
  unsigned short h8[8], l8[8];
#pragma unroll
  for (int e = 0; e < 8; ++e) {
    const unsigned short hh = f2bf(f[e]);
    h8[e] = hh;
    l8[e] = f2bf(f[e] - bf2f(hh));
  }
  hi = *(bf16x8*)h8;
  lo = *(bf16x8*)l8;
}

// ------------------------------------------------------------------
// Pack concatenated weights [Wh | Wx] into fragment-major bf16 hi/lo,
// gate-interleaved n-permutation: srow(n) = (n&3)*1024 + (n>>6)*16 + ((n>>2)&15)
// pk[((nt*KS + ks)*2 + hilo)*512 + l*8 + e] = src[srow(nt*16+(l&15))][ks*32+(l>>4)*8+e]
// ------------------------------------------------------------------
__global__ __launch_bounds__(256)
void pack_w2(const float* __restrict__ Wh, const float* __restrict__ Wx,
             unsigned short* __restrict__ pk, int Kh, int Kx) {
  const int KS = (Kh + Kx) >> 5;
  const int idx = blockIdx.x * 256 + threadIdx.x;
  const int total = 256 * KS * 64;
  if (idx >= total) return;
  const int l = idx & 63;
  const int t2 = idx >> 6;
  const int ks = t2 % KS;
  const int nt = t2 / KS;
  const int n = (nt << 4) + (l & 15);
  const int srow = ((n & 3) << 10) + ((n >> 6) << 4) + ((n >> 2) & 15);
  const int col = (ks << 5) + ((l >> 4) << 3);
  const float* src = (col < Kh) ? (Wh + (size_t)srow * Kh + col)
                                : (Wx + (size_t)srow * Kx + (col - Kh));
  unsigned short hi[8], lo[8];
#pragma unroll
  for (int e = 0; e < 8; ++e) {
    const float v = src[e];
    const unsigned short h = f2bf(v);
    hi[e] = h;
    lo[e] = f2bf(v - bf2f(h));
  }
  const size_t base = (((size_t)nt * KS + ks) * 2) * 512 + (size_t)l * 8;
  *(uint4*)(pk + base) = *(const uint4*)hi;
  *(uint4*)(pk + base + 512) = *(const uint4*)lo;
}

// LDS buffer layout (per 64KB buffer):
//  [0, 32768):      W block: nt*8192 + ksl*2048 + hilo*1024 + lane*16
//  [32768, 65536):  A block bf16: plane*16384 + row*256 + ((seg16 ^ (row&15))<<4)
//                or x block fp32: row*512 + ((seg32 ^ (row&15))<<5)  (rows 0..63)

__device__ __forceinline__ void comp_bf16(const char* buf, int ngoff, int arb, int l4, int l15,
                                          f32x4& acc0, f32x4& acc1) {
#pragma unroll
  for (int ksl = 0; ksl < 4; ++ksl) {
    const bf16x8 wh = *(const bf16x8*)(buf + ngoff + ksl * 2048);
    const bf16x8 wl = *(const bf16x8*)(buf + ngoff + ksl * 2048 + 1024);
    const int so = (((ksl << 2) + l4) ^ l15) << 4;
    const bf16x8 ah0 = *(const bf16x8*)(buf + arb + so);
    const bf16x8 al0 = *(const bf16x8*)(buf + arb + so + 16384);
    const bf16x8 ah1 = *(const bf16x8*)(buf + arb + so + 4096);
    const bf16x8 al1 = *(const bf16x8*)(buf + arb + so + 4096 + 16384);
    acc0 = __builtin_amdgcn_mfma_f32_16x16x32_bf16(ah0, wh, acc0, 0, 0, 0);
    acc0 = __builtin_amdgcn_mfma_f32_16x16x32_bf16(ah0, wl, acc0, 0, 0, 0);
    acc0 = __builtin_amdgcn_mfma_f32_16x16x32_bf16(al0, wh, acc0, 0, 0, 0);
    acc1 = __builtin_amdgcn_mfma_f32_16x16x32_bf16(ah1, wh, acc1, 0, 0, 0);
    acc1 = __builtin_amdgcn_mfma_f32_16x16x32_bf16(ah1, wl, acc1, 0, 0, 0);
    acc1 = __builtin_amdgcn_mfma_f32_16x16x32_bf16(al1, wh, acc1, 0, 0, 0);
  }
}

__device__ __forceinline__ void comp_x(const char* buf, int ngoff, int xrb, int l4, int l15,
                                       f32x4& acc0, f32x4& acc1) {
#pragma unroll
  for (int ksl = 0; ksl < 4; ++ksl) {
    const bf16x8 wh = *(const bf16x8*)(buf + ngoff + ksl * 2048);
    const bf16x8 wl = *(const bf16x8*)(buf + ngoff + ksl * 2048 + 1024);
    const int so = ((((ksl << 2) + l4) ^ l15) << 5);
    bf16x8 ah, al;
    split8(*(const float4*)(buf + xrb + so), *(const float4*)(buf + xrb + so + 16), ah, al);
    acc0 = __builtin_amdgcn_mfma_f32_16x16x32_bf16(ah, wh, acc0, 0, 0, 0);
    acc0 = __builtin_amdgcn_mfma_f32_16x16x32_bf16(ah, wl, acc0, 0, 0, 0);
    acc0 = __builtin_amdgcn_mfma_f32_16x16x32_bf16(al, wh, acc0, 0, 0, 0);
    split8(*(const float4*)(buf + xrb + so + 8192), *(const float4*)(buf + xrb + so + 8192 + 16), ah, al);
    acc1 = __builtin_amdgcn_mfma_f32_16x16x32_bf16(ah, wh, acc1, 0, 0, 0);
    acc1 = __builtin_amdgcn_mfma_f32_16x16x32_bf16(ah, wl, acc1, 0, 0, 0);
    acc1 = __builtin_amdgcn_mfma_f32_16x16x32_bf16(al, wh, acc1, 0, 0, 0);
  }
}

// ------------------------------------------------------------------
// Diagonal dual-layer step: WGs 0..127 run layer0 @ t, WGs 128..255 run
// layer1 @ t-1. 512 thr/WG. W AND A staged in LDS, double-buffered (128KB).
// ------------------------------------------------------------------
__global__ __launch_bounds__(512, 1)
void step_dual(int t,
               const float* __restrict__ x,
               const unsigned short* __restrict__ pk0,
               const unsigned short* __restrict__ pk1,
               unsigned short* __restrict__ h0s0, unsigned short* __restrict__ h0s1,
               unsigned short* __restrict__ h1s0, unsigned short* __restrict__ h1s1,
               const float* __restrict__ bih0, const float* __restrict__ bhh0,
               const float* __restrict__ bih1, const float* __restrict__ bhh1,
               float* __restrict__ c0, float* __restrict__ c1) {
  __shared__ __align__(16) char lds0[65536];
  __shared__ __align__(16) char lds1[65536];
  const int bid = blockIdx.x;
  const int layer = bid >> 7;
  if (layer == 0 && t >= TT) return;
  if (layer == 1 && t < 1) return;
  const int lbid = bid & 127;
  const int jg = lbid & 63, bh = lbid >> 6;
  const int tid = threadIdx.x;
  const int wid = tid >> 6, l = tid & 63;
  const int mh = wid & 1, ng = wid >> 1;
  const int l15 = l & 15, l4 = l >> 4;
  const int nl = (ng << 4) + l15;

  // per-layer configuration
  const int KS = layer ? 64 : 48;
  const int NB = KS >> 2;            // 12 or 16 blocks of 4 k-slices
  const unsigned short* pk = layer ? pk1 : pk0;
  const unsigned short* a1;          // prev-h of own layer (hi base; lo at +LOOFF)
  const unsigned short* a2;          // layer1: h0[t-1]
  unsigned short* ho;
  float* cb;
  const float* bv0;
  const float* bv1;
  if (layer == 0) {
    a1 = (t & 1) ? h0s0 : h0s1;
    ho = (t & 1) ? h0s1 : h0s0;
    a2 = a1;
    cb = c0; bv0 = bih0; bv1 = bhh0;
  } else {
    const int u = t - 1;
    a1 = (u & 1) ? h1s0 : h1s1;
    ho = (u & 1) ? h1s1 : h1s0;
    a2 = (t & 1) ? h0s0 : h0s1;
    cb = c1; bv0 = bih1; bv1 = bhh1;
  }

  // staging maps
  const int arow = tid >> 3;             // 0..63 (local A row)
  const int aseg = tid & 7;
  const int swA = arow & 15;
  const size_t growA = (size_t)((bh << 6) + arow);
  const unsigned short* a1g = a1 + growA * HH;
  const unsigned short* a2g = a2 + growA * HH;
  const float* xg = x + (size_t)t * DD + growA * XROW;

  const unsigned short* pkc0 = pk + ((size_t)(jg * 4 + 0) * KS) * 1024 + (size_t)tid * 8;
  const unsigned short* pkc1 = pk + ((size_t)(jg * 4 + 1) * KS) * 1024 + (size_t)tid * 8;
  const unsigned short* pkc2 = pk + ((size_t)(jg * 4 + 2) * KS) * 1024 + (size_t)tid * 8;
  const unsigned short* pkc3 = pk + ((size_t)(jg * 4 + 3) * KS) * 1024 + (size_t)tid * 8;

  // LDS write offsets
  const int aw0 = 32768 + arow * 256 + ((aseg ^ swA) << 4);
  const int aw1 = 32768 + arow * 256 + (((aseg + 8) ^ swA) << 4);
  const int xw0 = 32768 + arow * 512 + ((((aseg) >> 1) ^ swA) << 5) + ((aseg & 1) << 4);
  const int xw1 = 32768 + arow * 512 + ((((aseg + 8) >> 1) ^ swA) << 5) + ((aseg & 1) << 4);
  const int xw2 = 32768 + arow * 512 + ((((aseg + 16) >> 1) ^ swA) << 5) + ((aseg & 1) << 4);
  const int xw3 = 32768 + arow * 512 + ((((aseg + 24) >> 1) ^ swA) << 5) + ((aseg & 1) << 4);

  // LDS read offsets
  const int ngoff = ng * 8192 + l * 16;
  const int arb = 32768 + (mh * 32 + l15) * 256;
  const int xrb = 32768 + (mh * 32 + l15) * 512;

  f32x4 acc0 = (f32x4)(0.f), acc1 = (f32x4)(0.f);
  uint4 qw0, qw1, qw2, qw3, qa0, qa1, qa2, qa3;

#define LOADW(bb) do {                                        \
    qw0 = *(const uint4*)(pkc0 + (size_t)(bb) * 4096);        \
    qw1 = *(const uint4*)(pkc1 + (size_t)(bb) * 4096);        \
    qw2 = *(const uint4*)(pkc2 + (size_t)(bb) * 4096);        \
    qw3 = *(const uint4*)(pkc3 + (size_t)(bb) * 4096);        \
  } while (0)

#define LOADA(bb) do {                                                         \
    if ((bb) < 8) {                                                            \
      const unsigned short* s_ = a1g + (size_t)(bb) * 128 + (size_t)aseg * 8;  \
      qa0 = *(const uint4*)s_;            qa1 = *(const uint4*)(s_ + 64);      \
      qa2 = *(const uint4*)(s_ + LOOFF);  qa3 = *(const uint4*)(s_ + LOOFF + 64); \
    } else if (layer == 1) {                                                   \
      const unsigned short* s_ = a2g + (size_t)((bb) - 8) * 128 + (size_t)aseg * 8; \
      qa0 = *(const uint4*)s_;            qa1 = *(const uint4*)(s_ + 64);      \
      qa2 = *(const uint4*)(s_ + LOOFF);  qa3 = *(const uint4*)(s_ + LOOFF + 64); \
    } else {                                                                   \
      const float* s_ = xg + (size_t)((bb) - 8) * 128;                         \
      qa0 = *(const uint4*)(s_ + aseg * 4);        qa1 = *(const uint4*)(s_ + (aseg + 8) * 4); \
      qa2 = *(const uint4*)(s_ + (aseg + 16) * 4); qa3 = *(const uint4*)(s_ + (aseg + 24) * 4); \
    }                                                                          \
  } while (0)

#define WRITEB(buf, bb) do {                                  \
    *(uint4*)((buf) + tid * 16)         = qw0;                \
    *(uint4*)((buf) + 8192 + tid * 16)  = qw1;                \
    *(uint4*)((buf) + 16384 + tid * 16) = qw2;                \
    *(uint4*)((buf) + 24576 + tid * 16) = qw3;                \
    if ((bb) < 8 || layer == 1) {                             \
      *(uint4*)((buf) + aw0) = qa0; *(uint4*)((buf) + aw1) = qa1; \
      *(uint4*)((buf) + aw0 + 16384) = qa2; *(uint4*)((buf) + aw1 + 16384) = qa3; \
    } else {                                                  \
      *(uint4*)((buf) + xw0) = qa0; *(uint4*)((buf) + xw1) = qa1; \
      *(uint4*)((buf) + xw2) = qa2; *(uint4*)((buf) + xw3) = qa3; \
    }                                                         \
  } while (0)

  // prologue: stage block 0
  LOADW(0); LOADA(0);
  WRITEB(lds0, 0);
  __syncthreads();

  for (int b = 0; b < NB; ++b) {
    char* cbuf_ = (b & 1) ? lds1 : lds0;
    char* nbuf_ = (b & 1) ? lds0 : lds1;
    if (b + 1 < NB) { LOADW(b + 1); LOADA(b + 1); }
    if (b < 8 || layer == 1) comp_bf16(cbuf_, ngoff, arb, l4, l15, acc0, acc1);
    else                     comp_x(cbuf_, ngoff, xrb, l4, l15, acc0, acc1);
    if (b + 1 < NB) WRITEB(nbuf_, b + 1);
    __syncthreads();
  }
#undef LOADW
#undef LOADA
#undef WRITEB

  // epilogue: bias + cell + h store (quad shfl gather: g = nl&3)
  const int n = (jg << 6) + nl;
  const int srow = ((n & 3) << 10) + ((n >> 6) << 4) + ((n >> 2) & 15);
  const float bn = bv0[srow] + bv1[srow];
  const int g = nl & 3;
  const int j = (jg << 4) + (nl >> 2);
  f32x4 accs[2] = {acc0, acc1};
#pragma unroll
  for (int mt = 0; mt < 2; ++mt) {
#pragma unroll
    for (int r = 0; r < 4; ++r) {
      const float v = accs[mt][r] + bn;
      const float v1 = __shfl_xor(v, 1);
      const float v2 = __shfl_xor(v, 2);
      const float v3 = __shfl_xor(v, 3);
      if (g == 0) {
        const int b = (bh << 6) + (mh << 5) + (mt << 4) + (l4 << 2) + r;
        const float si = sigmoid_fast(v);
        const float sf = sigmoid_fast(v1);
        const float tg = tanh_fast(v2);
        const float so = sigmoid_fast(v3);
        const size_t ci = (size_t)b * HH + j;
        const float cn = sf * cb[ci] + si * tg;
        cb[ci] = cn;
        const float h = so * tanh_fast(cn);
        const unsigned short hh = f2bf(h);
        ho[(size_t)b * HH + j] = hh;
        ho[LOOFF + (size_t)b * HH + j] = f2bf(h - bf2f(hh));
      }
    }
  }
}

// ------------------------------------------------------------------
// FC from hi/lo h slot
// ------------------------------------------------------------------
__global__ __launch_bounds__(256)
void fc_hilo(const unsigned short* __restrict__ hhi, const unsigned short* __restrict__ hlo,
             const float* __restrict__ fcw, const float* __restrict__ fcb,
             float* __restrict__ out) {
  const int gw = (int)((blockIdx.x * 256 + threadIdx.x) >> 6);
  const int lane = threadIdx.x & 63;
  const int b = gw / CO;
  const int n = gw - b * CO;
  const unsigned short* hp = hhi + (size_t)b * HH;
  const unsigned short* lp = hlo + (size_t)b * HH;
  const float* wp = fcw + (size_t)n * HH;
  float s = 0.f;
  for (int k = lane; k < HH; k += 64) s += (bf2f(hp[k]) + bf2f(lp[k])) * wp[k];
#pragma unroll
  for (int off = 32; off; off >>= 1) s += __shfl_down(s, off);
  if (lane == 0) out[b * CO + n] = s + fcb[n];
}

// ==================================================================
// Fallback fp32 path (round-2 kernels, used only if ws_size is small)
// ==================================================================
__global__ __launch_bounds__(256)
void gemm_bias(const float* __restrict__ A, long long sOut, long long sIn, int lt,
               const float* __restrict__ W,
               const float* __restrict__ b0, const float* __restrict__ b1,
               float* __restrict__ C, int N, int K) {
  __shared__ float as[16][64];
  __shared__ float wsh[16][64];
  const int tid = threadIdx.x;
  const int bm = blockIdx.y << 6;
  const int bn = blockIdx.x << 6;
  const int tr = (tid >> 4) << 2;
  const int tc = (tid & 15) << 2;
  const int lrow = tid >> 2;
  const int lk4 = (tid & 3) << 2;
  const int msk = (1 << lt) - 1;
  const int r = bm + lrow;
  const float* ap = A + (size_t)(r >> lt) * sOut + (size_t)(r & msk) * sIn + lk4;
  const float* wp = W + (size_t)(bn + lrow) * K + lk4;
  float acc[4][4] = {};
  for (int k0 = 0; k0 < K; k0 += 16) {
    const float4 av = *(const float4*)(ap + k0);
    const float4 wv = *(const float4*)(wp + k0);
    __syncthreads();
    as[lk4 + 0][lrow] = av.x; as[lk4 + 1][lrow] = av.y;
    as[lk4 + 2][lrow] = av.z; as[lk4 + 3][lrow] = av.w;
    wsh[lk4 + 0][lrow] = wv.x; wsh[lk4 + 1][lrow] = wv.y;
    wsh[lk4 + 2][lrow] = wv.z; wsh[lk4 + 3][lrow] = wv.w;
    __syncthreads();
#pragma unroll
    for (int k = 0; k < 16; ++k) {
      const float4 a = *(const float4*)&as[k][tr];
      const float4 b = *(const float4*)&wsh[k][tc];
      acc[0][0] += a.x * b.x; acc[0][1] += a.x * b.y; acc[0][2] += a.x * b.z; acc[0][3] += a.x * b.w;
      acc[1][0] += a.y * b.x; acc[1][1] += a.y * b.y; acc[1][2] += a.y * b.z; acc[1][3] += a.y * b.w;
      acc[2][0] += a.z * b.x; acc[2][1] += a.z * b.y; acc[2][2] += a.z * b.z; acc[2][3] += a.z * b.w;
      acc[3][0] += a.w * b.x; acc[3][1] += a.w * b.y; acc[3][2] += a.w * b.z; acc[3][3] += a.w * b.w;
    }
  }
  const float* bp0 = b0 + bn + tc;
  const float* bp1 = b1 + bn + tc;
#pragma unroll
  for (int i = 0; i < 4; ++i) {
    float* cp = C + (size_t)(bm + tr + i) * N + bn + tc;
#pragma unroll
    for (int j = 0; j < 4; ++j) cp[j] = acc[i][j] + bp0[j] + bp1[j];
  }
}

__global__ __launch_bounds__(256)
void lstm_step(const float* __restrict__ gx, long long gxstride,
               const float* __restrict__ whh,
               const float* __restrict__ hprev, long long pstride,
               float* __restrict__ hnext, long long nstride,
               float* __restrict__ cbuf) {
  __shared__ float hs[32][16];
  __shared__ float wsm[32][4][32];
  const int tid = threadIdx.x;
  const int jt = blockIdx.x << 5;
  const int bm = blockIdx.y << 4;
  const int col = tid & 31;
  const int rp = (tid >> 5) << 1;
  const int hr = tid >> 4;
  const int hk = (tid & 15) << 1;
  const int wrow = tid & 127;
  const int wg = wrow >> 5;
  const int wc = wrow & 31;
  const int wk = (tid >> 7) << 4;
  const float* wbase = whh + (size_t)(wg * HH + jt + wc) * HH + wk;
  const float* hbase = hprev + (size_t)(bm + hr) * pstride + hk;

  float acc[4][2] = {};
  for (int k0 = 0; k0 < HH; k0 += 32) {
    const float2 hv = *(const float2*)(hbase + k0);
    const float4 wv0 = *(const float4*)(wbase + k0);
    const float4 wv1 = *(const float4*)(wbase + k0 + 4);
    const float4 wv2 = *(const float4*)(wbase + k0 + 8);
    const float4 wv3 = *(const float4*)(wbase + k0 + 12);
    __syncthreads();
    hs[hk][hr] = hv.x; hs[hk + 1][hr] = hv.y;
    {
      const float wvv[16] = {wv0.x, wv0.y, wv0.z, wv0.w, wv1.x, wv1.y, wv1.z, wv1.w,
                             wv2.x, wv2.y, wv2.z, wv2.w, wv3.x, wv3.y, wv3.z, wv3.w};
#pragma unroll
      for (int i = 0; i < 16; ++i) wsm[wk + i][wg][wc] = wvv[i];
    }
    __syncthreads();
#pragma unroll
    for (int k = 0; k < 32; ++k) {
      const float2 a = *(const float2*)&hs[k][rp];
      const float wi = wsm[k][0][col];
      const float wf = wsm[k][1][col];
      const float wg_ = wsm[k][2][col];
      const float wo = wsm[k][3][col];
      acc[0][0] += a.x * wi;  acc[0][1] += a.y * wi;
      acc[1][0] += a.x * wf;  acc[1][1] += a.y * wf;
      acc[2][0] += a.x * wg_; acc[2][1] += a.y * wg_;
      acc[3][0] += a.x * wo;  acc[3][1] += a.y * wo;
    }
  }
#pragma unroll
  for (int rr = 0; rr < 2; ++rr) {
    const int b = bm + rp + rr;
    const int j = jt + col;
    const size_t gxo = (size_t)b * gxstride + j;
    const float gi = acc[0][rr] + gx[gxo];
    const float gf = acc[1][rr] + gx[gxo + HH];
    const float gg = acc[2][rr] + gx[gxo + 2 * HH];
    const float go = acc[3][rr] + gx[gxo + 3 * HH];
    const float si = 1.f / (1.f + expf(-gi));
    const float sf = 1.f / (1.f + expf(-gf));
    const float so = 1.f / (1.f + expf(-go));
    const size_t cidx = (size_t)b * HH + j;
    const float cn = sf * cbuf[cidx] + si * tanhf(gg);
    cbuf[cidx] = cn;
    hnext[(size_t)b * nstride + j] = so * tanhf(cn);
  }
}

__global__ __launch_bounds__(256)
void fc_kernel(const float* __restrict__ hlast, const float* __restrict__ fcw,
               const float* __restrict__ fcb, float* __restrict__ out) {
  const int gw = (int)((blockIdx.x * 256 + threadIdx.x) >> 6);
  const int lane = threadIdx.x & 63;
  const int b = gw / CO;
  const int n = gw - b * CO;
  const float* hp = hlast + (size_t)b * HH;
  const float* wp = fcw + (size_t)n * HH;
  float s = 0.f;
  for (int k = lane; k < HH; k += 64) s += hp[k] * wp[k];
#pragma unroll
  for (int off = 32; off; off >>= 1) s += __shfl_down(s, off);
  if (lane == 0) out[b * CO + n] = s + fcb[n];
}

// ==================================================================
extern "C" void kernel_launch(void* const* d_in, const int* in_sizes, int n_in,
                              void* d_out, int out_size, void* d_ws, size_t ws_size,
                              hipStream_t stream) {
  const float* x    = (const float*)d_in[0];
  const float* wih0 = (const float*)d_in[1];
  const float* whh0 = (const float*)d_in[2];
  const float* bih0 = (const float*)d_in[3];
  const float* bhh0 = (const float*)d_in[4];
  const float* wih1 = (const float*)d_in[5];
  const float* whh1 = (const float*)d_in[6];
  const float* bih1 = (const float*)d_in[7];
  const float* bhh1 = (const float*)d_in[8];
  const float* fcw  = (const float*)d_in[9];
  const float* fcb  = (const float*)d_in[10];
  float* out = (float*)d_out;

  // ---- MFMA-path workspace ----
  const size_t pk0B  = (size_t)256 * 48 * 1024 * 2;   // 25,165,824 B
  const size_t pk1B  = (size_t)256 * 64 * 1024 * 2;   // 33,554,432 B
  const size_t slotB = 2 * (size_t)BB * HH * 2;       // 524,288 B (hi+lo)
  const size_t cB    = (size_t)BB * HH * 4;           // 524,288 B
  const size_t needB = pk0B + pk1B + 4 * slotB + 2 * cB;  // 61,865,984 B

  if (needB <= ws_size) {
    char* p = (char*)d_ws;
    unsigned short* pk0  = (unsigned short*)p; p += pk0B;
    unsigned short* pk1  = (unsigned short*)p; p += pk1B;
    unsigned short* h0s0 = (unsigned short*)p; p += slotB;
    unsigned short* h1s0 = (unsigned short*)p; p += slotB;
    char* zblock = p;                         // h0s1, h1s1, c0, c1 (zeroed)
    unsigned short* h0s1 = (unsigned short*)p; p += slotB;
    unsigned short* h1s1 = (unsigned short*)p; p += slotB;
    float* c0 = (float*)p; p += cB;
    float* c1 = (float*)p; p += cB;

    hipMemsetAsync(zblock, 0, 2 * slotB + 2 * cB, stream);

    pack_w2<<<dim3((256 * 48 * 64) / 256), 256, 0, stream>>>(whh0, wih0, pk0, HH, DD);
    pack_w2<<<dim3((256 * 64 * 64) / 256), 256, 0, stream>>>(whh1, wih1, pk1, HH, HH);

    for (int t = 0; t <= TT; ++t) {
      step_dual<<<dim3(256), 512, 0, stream>>>(t, x, pk0, pk1,
                                               h0s0, h0s1, h1s0, h1s1,
                                               bih0, bhh0, bih1, bhh1, c0, c1);
    }

    // final u = 255 (odd) wrote slot[1] = h1s1
    fc_hilo<<<dim3((BB * CO * 64) / 256), 256, 0, stream>>>(h1s1, h1s1 + LOOFF,
                                                            fcw, fcb, out);
    return;
  }

  // ---------------- fallback fp32 path ----------------
  {
    int Tc2 = 64, lt2 = 6;
    while (Tc2 > 1) {
      size_t need = ((size_t)655360 * (size_t)Tc2 + 4u * 131072u + 1024u) * 4u;
      if (need <= ws_size) break;
      Tc2 >>= 1; --lt2;
    }
    float* ws  = (float*)d_ws;
    float* gxc = ws;
    float* hc  = gxc + (size_t)BB * Tc2 * G4H;
    float* c0  = hc + (size_t)BB * Tc2 * HH;
    float* c1  = c0 + (size_t)BB * HH;
    float* h2a = c1 + (size_t)BB * HH;
    float* h2b = h2a + (size_t)BB * HH;
    float* zb  = h2b + (size_t)BB * HH;

    hipMemsetAsync(zb, 0, HH * sizeof(float), stream);
    hipMemsetAsync(c0, 0, (size_t)BB * HH * sizeof(float), stream);
    hipMemsetAsync(c1, 0, (size_t)BB * HH * sizeof(float), stream);

    const dim3 gGemm(G4H / 64, (BB * Tc2) / 64);
    const dim3 gStep(HH / 32, BB / 16);
    const long long gxs = (long long)Tc2 * G4H;
    const long long hcs = (long long)Tc2 * HH;

    const int nChunks = TT / Tc2;
    for (int ci = 0; ci < nChunks; ++ci) {
      const int t0 = ci * Tc2;
      gemm_bias<<<gGemm, 256, 0, stream>>>(x + (size_t)t0 * DD, (long long)TT * DD,
                                           (long long)DD, lt2, wih0, bih0, bhh0,
                                           gxc, G4H, DD);
      for (int tl = 0; tl < Tc2; ++tl) {
        const int t = t0 + tl;
        const float* hprev;
        long long ps;
        if (t == 0) { hprev = zb; ps = 0; }
        else {
          const int ptl = (tl == 0) ? (Tc2 - 1) : (tl - 1);
          hprev = hc + (size_t)ptl * HH; ps = hcs;
        }
        lstm_step<<<gStep, 256, 0, stream>>>(gxc + (size_t)tl * G4H, gxs, whh0,
                                             hprev, ps, hc + (size_t)tl * HH, hcs, c0);
      }
      gemm_bias<<<gGemm, 256, 0, stream>>>(hc, hcs, (long long)HH, lt2,
                                           wih1, bih1, bhh1, gxc, G4H, HH);
      for (int tl = 0; tl < Tc2; ++tl) {
        const int t = t0 + tl;
        const float* hprev;
        long long ps;
        if (t == 0) { hprev = zb; ps = 0; }
        else { hprev = ((t - 1) & 1) ? h2b : h2a; ps = HH; }
        float* hnext = (t & 1) ? h2b : h2a;
        lstm_step<<<gStep, 256, 0, stream>>>(gxc + (size_t)tl * G4H, gxs, whh1,
                                             hprev, ps, hnext, HH, c1);
      }
    }
    fc_kernel<<<dim3((BB * CO * 64) / 256), 256, 0, stream>>>(h2b, fcw, fcb, out);
  }
}